// Round 2
// baseline (14839.058 us; speedup 1.0000x reference)
//
#include <hip/hip_runtime.h>
#include <hip/hip_bf16.h>
#include <math.h>

#define BATCH 8
#define SEQL  4096
#define DM    256
#define DI    512

// ---------------- im2col: patchify + hilbert permute (chunk rows) ----------------
__global__ __launch_bounds__(256) void im2col_chunk(
    const float* __restrict__ x, const int* __restrict__ perm,
    float* __restrict__ P, int l0, int lg) {
  int idx = blockIdx.x * 256 + threadIdx.x;   // CR*192
  int k = idx % 192;
  int rb = idx / 192;
  int b = rb >> lg;
  int l = l0 + (rb & ((1 << lg) - 1));
  int j = perm[l];
  int py = j >> 6, px = j & 63;
  int c = k / 64;
  int uu = (k & 63) >> 3;
  int v = k & 7;
  P[(size_t)rb * 192 + k] =
      x[(((size_t)b * 3 + c) * 512 + (size_t)(py * 8 + uu)) * 512 + px * 8 + v];
}

// ---------------- fp32 tiled GEMM: C[M,N] = A[M,K] * W[N,K]^T (+bias) ----------------
// BM=BN=64, BK=32, 256 threads, 4x4 per thread. Mrows mult of 64, N mult of 64, K mult of 32.
template<bool BIAS>
__global__ __launch_bounds__(256) void gemm_nt(
    const float* __restrict__ A, const float* __restrict__ W,
    const float* __restrict__ bias, float* __restrict__ C,
    int N, int K) {
  __shared__ float As[32][68];
  __shared__ float Ws[32][68];
  const int bm = blockIdx.y * 64;
  const int bn = blockIdx.x * 64;
  const int tid = threadIdx.x;
  const int tx = tid & 15, ty = tid >> 4;
  const int kr = tid & 31, mr = tid >> 5;
  float acc[4][4] = {};
  for (int k0 = 0; k0 < K; k0 += 32) {
    #pragma unroll
    for (int r = 0; r < 8; ++r) {
      As[kr][mr + r * 8] = A[(size_t)(bm + mr + r * 8) * K + k0 + kr];
      Ws[kr][mr + r * 8] = W[(size_t)(bn + mr + r * 8) * K + k0 + kr];
    }
    __syncthreads();
    #pragma unroll
    for (int k = 0; k < 32; ++k) {
      float4 av = *(const float4*)&As[k][ty * 4];
      float4 wv = *(const float4*)&Ws[k][tx * 4];
      const float* ap = (const float*)&av;
      const float* wp = (const float*)&wv;
      #pragma unroll
      for (int i = 0; i < 4; ++i)
        #pragma unroll
        for (int jj = 0; jj < 4; ++jj)
          acc[i][jj] = fmaf(ap[i], wp[jj], acc[i][jj]);
    }
    __syncthreads();
  }
  #pragma unroll
  for (int i = 0; i < 4; ++i) {
    size_t cro = (size_t)(bm + ty * 4 + i) * N + bn + tx * 4;
    #pragma unroll
    for (int jj = 0; jj < 4; ++jj) {
      float v = acc[i][jj];
      if (BIAS) v += bias[bn + tx * 4 + jj];
      C[cro + jj] = v;
    }
  }
}

// ---------------- RMSNorm: gather global emb rows -> chunk u ----------------
__global__ __launch_bounds__(256) void rmsnorm_chunk(
    const float* __restrict__ emb, const float* __restrict__ w,
    float* __restrict__ u, int l0, int lg) {
  int rb = blockIdx.x;
  int t = threadIdx.x;
  size_t grow = ((size_t)(rb >> lg) << 12) + l0 + (rb & ((1 << lg) - 1));
  float v = emb[grow * 256 + t];
  float sq = v * v;
  for (int m = 1; m < 64; m <<= 1) sq += __shfl_xor(sq, m, 64);
  __shared__ float wsum[4];
  if ((t & 63) == 0) wsum[t >> 6] = sq;
  __syncthreads();
  float tot = wsum[0] + wsum[1] + wsum[2] + wsum[3];
  u[(size_t)rb * 256 + t] = v * rsqrtf(tot * (1.f / 256.f) + 1e-5f) * w[t];
}

// ---------------- causal depthwise conv (K=4) + bias + silu, with history ----------------
__global__ __launch_bounds__(256) void conv_chunk(
    const float* __restrict__ xraw, const float* __restrict__ cstate,
    const float* __restrict__ cw, const float* __restrict__ cb,
    float* __restrict__ xc, int l0, int lg) {
  int idx = blockIdx.x * 256 + threadIdx.x;   // CR*512
  int d = idx & 511;
  int rb = idx >> 9;
  int b = rb >> lg;
  int loff = rb & ((1 << lg) - 1);
  int l = l0 + loff;
  float acc = cb[d];
  #pragma unroll
  for (int k = 0; k < 4; ++k) {
    int ls = l - 3 + k;
    if (ls >= 0) {
      int lo = ls - l0;
      float xv;
      if (lo >= 0) xv = xraw[((size_t)(b << lg) + lo) * 512 + d];
      else         xv = cstate[((size_t)b * 3 + (lo + 3)) * 512 + d];
      acc = fmaf(xv, cw[d * 4 + k], acc);
    }
  }
  float sig = 1.f / (1.f + __expf(-acc));
  xc[(size_t)rb * 512 + d] = acc * sig;
}

// save last 3 rows of xraw per batch as next chunk's conv history
__global__ __launch_bounds__(256) void save_hist(
    const float* __restrict__ xraw, float* __restrict__ cstate, int lg) {
  int idx = blockIdx.x * 256 + threadIdx.x;   // 8*3*512
  int d = idx & 511;
  int r = (idx >> 9) % 3;
  int b = (idx >> 9) / 3;
  int CL = 1 << lg;
  cstate[idx] = xraw[((size_t)(b << lg) + CL - 3 + r) * 512 + d];
}

// ---------------- pad x_proj_w (48x512) to 64x512 ----------------
__global__ __launch_bounds__(256) void pad_xproj_kernel(
    const float* __restrict__ xpw, float* __restrict__ w64) {
  int idx = blockIdx.x * 256 + threadIdx.x;  // 64*512
  int n = idx >> 9;
  w64[idx] = (n < 48) ? xpw[idx] : 0.f;
}

// ---------------- dt = softplus(xdbl[:, :16] @ dt_w^T + dt_b) ----------------
__global__ __launch_bounds__(256) void dt_chunk(
    const float* __restrict__ xdbl, const float* __restrict__ dtw,
    const float* __restrict__ dtbias, float* __restrict__ dtv) {
  int idx = blockIdx.x * 256 + threadIdx.x;   // CR*512
  int d = idx & 511;
  int row = idx >> 9;
  const float* xd = xdbl + (size_t)row * 64;
  float a = dtbias[d];
  #pragma unroll
  for (int r = 0; r < 16; ++r) a = fmaf(xd[r], dtw[d * 16 + r], a);
  dtv[idx] = (a > 20.f) ? a : log1pf(__expf(a));
}

// ---------------- selective scan (chunked, carries h), fused z-gating ----------------
__global__ __launch_bounds__(256) void scan_chunk(
    const float* __restrict__ dtv, const float* __restrict__ xdbl,
    const float* __restrict__ xc, const float* __restrict__ z,
    const float* __restrict__ A_log, const float* __restrict__ D_skip,
    float* __restrict__ y, float* __restrict__ hstate, int CL, int first) {
  int b = blockIdx.y;
  int g = threadIdx.x >> 4;
  int n = threadIdx.x & 15;
  int d = blockIdx.x * 16 + g;
  float An = -__expf(A_log[d * 16 + n]);
  float Dd = D_skip[d];
  size_t hidx = ((size_t)b * 512 + d) * 16 + n;
  float h = first ? 0.f : hstate[hidx];
  size_t rb = (size_t)b * CL;
  for (int l = 0; l < CL; ++l, ++rb) {
    float dts = dtv[rb * 512 + d];
    float xv  = xc[rb * 512 + d];
    float Bn  = xdbl[rb * 64 + 16 + n];
    float Cn  = xdbl[rb * 64 + 32 + n];
    float dA  = __expf(dts * An);
    h = fmaf(h, dA, (dts * xv) * Bn);
    float acc = h * Cn;
    acc += __shfl_xor(acc, 1, 64);
    acc += __shfl_xor(acc, 2, 64);
    acc += __shfl_xor(acc, 4, 64);
    acc += __shfl_xor(acc, 8, 64);
    if (n == 0) {
      float zv = z[rb * 512 + d];
      float sig = 1.f / (1.f + __expf(-zv));
      y[rb * 512 + d] = fmaf(xv, Dd, acc) * (zv * sig);
    }
  }
  hstate[hidx] = h;
}

// ---------------- scatter chunk rows into global emb ----------------
template<bool ADD>
__global__ __launch_bounds__(256) void scatter_emb(
    const float* __restrict__ E, float* __restrict__ emb, int l0, int lg) {
  int rb = blockIdx.x;
  int t = threadIdx.x;
  size_t grow = ((size_t)(rb >> lg) << 12) + l0 + (rb & ((1 << lg) - 1));
  float v = E[(size_t)rb * 256 + t];
  if (ADD) emb[grow * 256 + t] += v;
  else     emb[grow * 256 + t] = v;
}

// ---------------- final rmsnorm fused with pooling partials ----------------
__global__ __launch_bounds__(256) void normpool_partial(
    const float* __restrict__ emb, const float* __restrict__ nf,
    float* __restrict__ part) {
  int b = blockIdx.x, ch = blockIdx.y, t = threadIdx.x;
  __shared__ float wsum[4];
  float acc = 0.f;
  for (int l = ch * 128; l < ch * 128 + 128; ++l) {
    size_t row = (size_t)b * 4096 + l;
    float v = emb[row * 256 + t];
    float sq = v * v;
    for (int m = 1; m < 64; m <<= 1) sq += __shfl_xor(sq, m, 64);
    if ((t & 63) == 0) wsum[t >> 6] = sq;
    __syncthreads();
    float tot = wsum[0] + wsum[1] + wsum[2] + wsum[3];
    __syncthreads();
    acc += v * rsqrtf(tot * (1.f / 256.f) + 1e-5f);
  }
  part[((size_t)b * 32 + ch) * 256 + t] = acc * nf[t];
}

__global__ __launch_bounds__(256) void pool_reduce_kernel(
    const float* __restrict__ part, float* __restrict__ pooled) {
  int b = blockIdx.x, t = threadIdx.x;
  float s = 0.f;
  for (int c = 0; c < 32; ++c) s += part[((size_t)b * 32 + c) * 256 + t];
  pooled[b * 256 + t] = s * (1.f / 4096.f);
}

__global__ __launch_bounds__(128) void head_kernel(
    const float* __restrict__ pooled, const float* __restrict__ hw,
    const float* __restrict__ hb, float* __restrict__ out) {
  int t = threadIdx.x;
  if (t < 80) {
    int b = t / 10, c = t % 10;
    float a = hb[c];
    for (int dd = 0; dd < 256; ++dd) a = fmaf(pooled[b * 256 + dd], hw[c * 256 + dd], a);
    out[t] = a;
  }
}

extern "C" void kernel_launch(void* const* d_in, const int* in_sizes, int n_in,
                              void* d_out, int out_size, void* d_ws, size_t ws_size,
                              hipStream_t stream) {
  const float* x         = (const float*)d_in[0];
  const int*   perm      = (const int*)d_in[1];
  const float* patch_w   = (const float*)d_in[2];
  const float* patch_b   = (const float*)d_in[3];
  const float* norm_w    = (const float*)d_in[4];
  const float* in_proj_w = (const float*)d_in[5];
  const float* conv_w    = (const float*)d_in[6];
  const float* conv_b    = (const float*)d_in[7];
  const float* x_proj_w  = (const float*)d_in[8];
  const float* dt_w      = (const float*)d_in[9];
  const float* dt_b      = (const float*)d_in[10];
  const float* A_log     = (const float*)d_in[11];
  const float* D_skip    = (const float*)d_in[12];
  const float* out_w     = (const float*)d_in[13];
  const float* norm_f    = (const float*)d_in[14];
  const float* head_w    = (const float*)d_in[15];
  const float* head_b    = (const float*)d_in[16];
  float* outp = (float*)d_out;

  const size_t M = (size_t)BATCH * SEQL;  // 32768
  float* ws     = (float*)d_ws;
  float* emb    = ws;                       // M*256 (persistent fp32 residual)
  float* hstate = emb + M * 256;            // 8*512*16
  float* cstate = hstate + 8 * 512 * 16;    // 8*3*512
  float* w64    = cstate + 8 * 3 * 512;     // 64*512
  float* part   = w64 + 64 * 512;           // 8*32*256
  float* pooled = part + 8 * 32 * 256;      // 8*256
  float* cbase  = pooled + 8 * 256;

  // pick largest chunk length CL (power of two) whose footprint fits ws_size
  size_t fixedF = (size_t)(cbase - ws);
  int CL = 4096;
  while (CL > 32) {
    size_t need = (fixedF + (size_t)8 * CL * 2880) * sizeof(float);
    if (need <= ws_size) break;
    CL >>= 1;
  }
  int lg = 31 - __builtin_clz((unsigned)CL);
  int nch = 4096 / CL;
  int CR = 8 * CL;   // chunk rows (all batches)

  float* u    = cbase;                      // CR*256
  float* xraw = u + (size_t)CR * 256;       // CR*512  (alias: P = im2col patches CR*192)
  float* z    = xraw + (size_t)CR * 512;    // CR*512  (alias: E = pre-scatter GEMM out CR*256)
  float* xc   = z + (size_t)CR * 512;       // CR*512
  float* xdbl = xc + (size_t)CR * 512;      // CR*64
  float* dtv  = xdbl + (size_t)CR * 64;     // CR*512
  float* y    = dtv + (size_t)CR * 512;     // CR*512
  float* P = xraw;
  float* E = z;

  // ---- patch embed (+ hilbert permute) ----
  for (int c = 0; c < nch; ++c) {
    int l0 = c * CL;
    im2col_chunk<<<CR * 192 / 256, 256, 0, stream>>>(x, perm, P, l0, lg);
    gemm_nt<true><<<dim3(256 / 64, CR / 64), 256, 0, stream>>>(P, patch_w, patch_b, E, 256, 192);
    scatter_emb<false><<<CR, 256, 0, stream>>>(E, emb, l0, lg);
  }

  // ---- layers ----
  for (int layer = 0; layer < 4; ++layer) {
    pad_xproj_kernel<<<64 * 512 / 256, 256, 0, stream>>>(
        x_proj_w + (size_t)layer * 48 * 512, w64);
    const float* Wx = in_proj_w + (size_t)layer * 1024 * 256;
    const float* Wz = Wx + (size_t)512 * 256;
    for (int c = 0; c < nch; ++c) {
      int l0 = c * CL;
      rmsnorm_chunk<<<CR, 256, 0, stream>>>(emb, norm_w + layer * 256, u, l0, lg);
      gemm_nt<false><<<dim3(512 / 64, CR / 64), 256, 0, stream>>>(u, Wx, nullptr, xraw, 512, 256);
      gemm_nt<false><<<dim3(512 / 64, CR / 64), 256, 0, stream>>>(u, Wz, nullptr, z, 512, 256);
      conv_chunk<<<CR * 512 / 256, 256, 0, stream>>>(
          xraw, cstate, conv_w + layer * 512 * 4, conv_b + layer * 512, xc, l0, lg);
      save_hist<<<48, 256, 0, stream>>>(xraw, cstate, lg);
      gemm_nt<false><<<dim3(1, CR / 64), 256, 0, stream>>>(xc, w64, nullptr, xdbl, 64, 512);
      dt_chunk<<<CR * 512 / 256, 256, 0, stream>>>(
          xdbl, dt_w + layer * 512 * 16, dt_b + layer * 512, dtv);
      scan_chunk<<<dim3(32, 8), 256, 0, stream>>>(
          dtv, xdbl, xc, z, A_log + layer * 512 * 16, D_skip + layer * 512,
          y, hstate, CL, c == 0 ? 1 : 0);
      gemm_nt<false><<<dim3(256 / 64, CR / 64), 256, 0, stream>>>(
          y, out_w + (size_t)layer * 256 * 512, nullptr, E, 256, 512);
      scatter_emb<true><<<CR, 256, 0, stream>>>(E, emb, l0, lg);
    }
  }

  // ---- final norm + pool + head ----
  normpool_partial<<<dim3(8, 32), 256, 0, stream>>>(emb, norm_f, part);
  pool_reduce_kernel<<<8, 256, 0, stream>>>(part, pooled);
  head_kernel<<<1, 128, 0, stream>>>(pooled, head_w, head_b, outp);
}

// Round 3
// 6165.993 us; speedup vs baseline: 2.4066x; 2.4066x over previous
//
#include <hip/hip_runtime.h>
#include <hip/hip_bf16.h>
#include <math.h>

#define BATCH 8
#define SEQL  4096

typedef unsigned short u16;
typedef short bf16x8 __attribute__((ext_vector_type(8)));
typedef float f32x4 __attribute__((ext_vector_type(4)));

__device__ __forceinline__ u16 bfr(float a) {
  unsigned u = __float_as_uint(a);
  return (u16)((u + 0x7FFFu + ((u >> 16) & 1u)) >> 16);
}
__device__ __forceinline__ void bsplit(float a, u16& h, u16& l) {
  u16 hb = bfr(a);
  float hf = __uint_as_float((unsigned)hb << 16);
  h = hb;
  l = bfr(a - hf);
}

// ---------------- generic fp32 -> bf16 hi/lo split ----------------
__global__ __launch_bounds__(256) void convert_split(
    const float* __restrict__ in, u16* __restrict__ hi, u16* __restrict__ lo, int n) {
  int i4 = (blockIdx.x * 256 + threadIdx.x) * 4;
  if (i4 >= n) return;
  float4 v = *(const float4*)(in + i4);
  u16 h0,l0,h1,l1,h2,l2,h3,l3;
  bsplit(v.x,h0,l0); bsplit(v.y,h1,l1); bsplit(v.z,h2,l2); bsplit(v.w,h3,l3);
  hi[i4]=h0; hi[i4+1]=h1; hi[i4+2]=h2; hi[i4+3]=h3;
  lo[i4]=l0; lo[i4+1]=l1; lo[i4+2]=l2; lo[i4+3]=l3;
}

// pad x_proj_w (48x512) to 64x512 and split
__global__ __launch_bounds__(256) void padxp_convert(
    const float* __restrict__ xpw, u16* __restrict__ hi, u16* __restrict__ lo) {
  int i4 = (blockIdx.x * 256 + threadIdx.x) * 4;   // over 64*512
  if (i4 >= 64 * 512) return;
  int row = i4 >> 9;
  float4 v = row < 48 ? *(const float4*)(xpw + i4) : make_float4(0.f,0.f,0.f,0.f);
  u16 h0,l0,h1,l1,h2,l2,h3,l3;
  bsplit(v.x,h0,l0); bsplit(v.y,h1,l1); bsplit(v.z,h2,l2); bsplit(v.w,h3,l3);
  hi[i4]=h0; hi[i4+1]=h1; hi[i4+2]=h2; hi[i4+3]=h3;
  lo[i4]=l0; lo[i4+1]=l1; lo[i4+2]=l2; lo[i4+3]=l3;
}

// ---------------- im2col: patchify + hilbert permute -> bf16 hi/lo ----------------
__global__ __launch_bounds__(256) void im2col_chunk(
    const float* __restrict__ x, const int* __restrict__ perm,
    u16* __restrict__ Ph, u16* __restrict__ Pl, int l0, int lg) {
  int idx = blockIdx.x * 256 + threadIdx.x;   // CR*192
  int k = idx % 192;
  int rb = idx / 192;
  int b = rb >> lg;
  int l = l0 + (rb & ((1 << lg) - 1));
  int j = perm[l];
  int py = j >> 6, px = j & 63;
  int c = k / 64;
  int uu = (k & 63) >> 3;
  int v = k & 7;
  float a = x[(((size_t)b * 3 + c) * 512 + (size_t)(py * 8 + uu)) * 512 + px * 8 + v];
  u16 h, lw; bsplit(a, h, lw);
  Ph[(size_t)rb * 192 + k] = h;
  Pl[(size_t)rb * 192 + k] = lw;
}

// ---------------- MFMA GEMM, 3-term bf16 split, fp32 accumulate ----------------
// C[M,N] = A[M,K] * W[N,K]^T (+bias). Tiles: BM=BN=64, BK=32, 256 thr (2x2 waves).
template<bool BIAS>
__global__ __launch_bounds__(256) void gemm_bf3(
    const u16* __restrict__ Ah, const u16* __restrict__ Al,
    const u16* __restrict__ Wh, const u16* __restrict__ Wl,
    const float* __restrict__ bias, float* __restrict__ C,
    int N, int K) {
  __shared__ u16 As_h[64 * 32], As_l[64 * 32], Ws_h[64 * 32], Ws_l[64 * 32];
  const int bm = blockIdx.y * 64, bn = blockIdx.x * 64;
  const int t = threadIdx.x;
  const int r = t >> 2, kq = (t & 3) * 8;
  const int lane = t & 63, w = t >> 6;
  const int wr = w >> 1, wc = w & 1;
  const int l15 = lane & 15, kg = lane >> 4;

  const int soff = r * 64 + ((kq * 2) ^ (((r >> 1) & 3) << 4));
  const int ar0 = wr * 32 + l15, ar1 = ar0 + 16;
  const int br0 = wc * 32 + l15, br1 = br0 + 16;
  const int fa0 = ar0 * 64 + ((kg * 16) ^ (((ar0 >> 1) & 3) << 4));
  const int fa1 = ar1 * 64 + ((kg * 16) ^ (((ar1 >> 1) & 3) << 4));
  const int fb0 = br0 * 64 + ((kg * 16) ^ (((br0 >> 1) & 3) << 4));
  const int fb1 = br1 * 64 + ((kg * 16) ^ (((br1 >> 1) & 3) << 4));

  f32x4 acc00 = {0.f,0.f,0.f,0.f}, acc01 = {0.f,0.f,0.f,0.f};
  f32x4 acc10 = {0.f,0.f,0.f,0.f}, acc11 = {0.f,0.f,0.f,0.f};

  const size_t arow = (size_t)(bm + r) * K;
  const size_t wrow = (size_t)(bn + r) * K;

  for (int k0 = 0; k0 < K; k0 += 32) {
    uint4 va_h = *(const uint4*)(Ah + arow + k0 + kq);
    uint4 va_l = *(const uint4*)(Al + arow + k0 + kq);
    uint4 vw_h = *(const uint4*)(Wh + wrow + k0 + kq);
    uint4 vw_l = *(const uint4*)(Wl + wrow + k0 + kq);
    __syncthreads();
    *(uint4*)((char*)As_h + soff) = va_h;
    *(uint4*)((char*)As_l + soff) = va_l;
    *(uint4*)((char*)Ws_h + soff) = vw_h;
    *(uint4*)((char*)Ws_l + soff) = vw_l;
    __syncthreads();
    bf16x8 ah0 = *(const bf16x8*)((const char*)As_h + fa0);
    bf16x8 ah1 = *(const bf16x8*)((const char*)As_h + fa1);
    bf16x8 al0 = *(const bf16x8*)((const char*)As_l + fa0);
    bf16x8 al1 = *(const bf16x8*)((const char*)As_l + fa1);
    bf16x8 bh0 = *(const bf16x8*)((const char*)Ws_h + fb0);
    bf16x8 bh1 = *(const bf16x8*)((const char*)Ws_h + fb1);
    bf16x8 bl0 = *(const bf16x8*)((const char*)Ws_l + fb0);
    bf16x8 bl1 = *(const bf16x8*)((const char*)Ws_l + fb1);
    acc00 = __builtin_amdgcn_mfma_f32_16x16x32_bf16(ah0, bh0, acc00, 0, 0, 0);
    acc01 = __builtin_amdgcn_mfma_f32_16x16x32_bf16(ah0, bh1, acc01, 0, 0, 0);
    acc10 = __builtin_amdgcn_mfma_f32_16x16x32_bf16(ah1, bh0, acc10, 0, 0, 0);
    acc11 = __builtin_amdgcn_mfma_f32_16x16x32_bf16(ah1, bh1, acc11, 0, 0, 0);
    acc00 = __builtin_amdgcn_mfma_f32_16x16x32_bf16(ah0, bl0, acc00, 0, 0, 0);
    acc01 = __builtin_amdgcn_mfma_f32_16x16x32_bf16(ah0, bl1, acc01, 0, 0, 0);
    acc10 = __builtin_amdgcn_mfma_f32_16x16x32_bf16(ah1, bl0, acc10, 0, 0, 0);
    acc11 = __builtin_amdgcn_mfma_f32_16x16x32_bf16(ah1, bl1, acc11, 0, 0, 0);
    acc00 = __builtin_amdgcn_mfma_f32_16x16x32_bf16(al0, bh0, acc00, 0, 0, 0);
    acc01 = __builtin_amdgcn_mfma_f32_16x16x32_bf16(al0, bh1, acc01, 0, 0, 0);
    acc10 = __builtin_amdgcn_mfma_f32_16x16x32_bf16(al1, bh0, acc10, 0, 0, 0);
    acc11 = __builtin_amdgcn_mfma_f32_16x16x32_bf16(al1, bh1, acc11, 0, 0, 0);
  }

  const int rowb = bm + wr * 32 + kg * 4;
  const int colb = bn + wc * 32 + l15;
  float bi0 = 0.f, bi1 = 0.f;
  if (BIAS) { bi0 = bias[colb]; bi1 = bias[colb + 16]; }
  #pragma unroll
  for (int q = 0; q < 4; ++q) {
    C[(size_t)(rowb + q) * N + colb]           = acc00[q] + bi0;
    C[(size_t)(rowb + q) * N + colb + 16]      = acc01[q] + bi1;
    C[(size_t)(rowb + 16 + q) * N + colb]      = acc10[q] + bi0;
    C[(size_t)(rowb + 16 + q) * N + colb + 16] = acc11[q] + bi1;
  }
}

// ---------------- RMSNorm -> bf16 hi/lo ----------------
__global__ __launch_bounds__(256) void rmsnorm_chunk(
    const float* __restrict__ emb, const float* __restrict__ w,
    u16* __restrict__ uh, u16* __restrict__ ul, int l0, int lg) {
  int rb = blockIdx.x;
  int t = threadIdx.x;
  size_t grow = ((size_t)(rb >> lg) << 12) + l0 + (rb & ((1 << lg) - 1));
  float v = emb[grow * 256 + t];
  float sq = v * v;
  for (int m = 1; m < 64; m <<= 1) sq += __shfl_xor(sq, m, 64);
  __shared__ float wsum[4];
  if ((t & 63) == 0) wsum[t >> 6] = sq;
  __syncthreads();
  float tot = wsum[0] + wsum[1] + wsum[2] + wsum[3];
  float val = v * rsqrtf(tot * (1.f / 256.f) + 1e-5f) * w[t];
  u16 h, l; bsplit(val, h, l);
  uh[(size_t)rb * 256 + t] = h;
  ul[(size_t)rb * 256 + t] = l;
}

// ---------------- causal depthwise conv + silu; fp32 + bf16 hi/lo ----------------
__global__ __launch_bounds__(256) void conv_chunk(
    const float* __restrict__ xraw, const float* __restrict__ cstate,
    const float* __restrict__ cw, const float* __restrict__ cb,
    float* __restrict__ xc, u16* __restrict__ xch, u16* __restrict__ xcl,
    int l0, int lg) {
  int idx = blockIdx.x * 256 + threadIdx.x;   // CR*512
  int d = idx & 511;
  int rb = idx >> 9;
  int b = rb >> lg;
  int l = l0 + (rb & ((1 << lg) - 1));
  float acc = cb[d];
  #pragma unroll
  for (int k = 0; k < 4; ++k) {
    int ls = l - 3 + k;
    if (ls >= 0) {
      int lo = ls - l0;
      float xv;
      if (lo >= 0) xv = xraw[((size_t)(b << lg) + lo) * 512 + d];
      else         xv = cstate[((size_t)b * 3 + (lo + 3)) * 512 + d];
      acc = fmaf(xv, cw[d * 4 + k], acc);
    }
  }
  float sig = 1.f / (1.f + __expf(-acc));
  float val = acc * sig;
  xc[(size_t)rb * 512 + d] = val;
  u16 h, lw; bsplit(val, h, lw);
  xch[(size_t)rb * 512 + d] = h;
  xcl[(size_t)rb * 512 + d] = lw;
}

__global__ __launch_bounds__(256) void save_hist(
    const float* __restrict__ xraw, float* __restrict__ cstate, int lg) {
  int idx = blockIdx.x * 256 + threadIdx.x;   // 8*3*512
  int d = idx & 511;
  int r = (idx >> 9) % 3;
  int b = (idx >> 9) / 3;
  int CL = 1 << lg;
  cstate[idx] = xraw[((size_t)(b << lg) + CL - 3 + r) * 512 + d];
}

// ---------------- dt = softplus(xdbl[:, :16] @ dt_w^T + dt_b) ----------------
__global__ __launch_bounds__(256) void dt_chunk(
    const float* __restrict__ xdbl, const float* __restrict__ dtw,
    const float* __restrict__ dtbias, float* __restrict__ dtv) {
  int idx = blockIdx.x * 256 + threadIdx.x;   // CR*512
  int d = idx & 511;
  int row = idx >> 9;
  const float* xd = xdbl + (size_t)row * 64;
  float a = dtbias[d];
  #pragma unroll
  for (int r = 0; r < 16; ++r) a = fmaf(xd[r], dtw[d * 16 + r], a);
  dtv[idx] = (a > 20.f) ? a : log1pf(__expf(a));
}

// ---------------- selective scan: LDS-tiled, double-buffered ----------------
// 16 channels x 16 states per block; 64-step tiles.
__global__ __launch_bounds__(256) void scan_chunk(
    const float* __restrict__ dtv, const float* __restrict__ xdbl,
    const float* __restrict__ xc, const float* __restrict__ z,
    const float* __restrict__ A_log, const float* __restrict__ D_skip,
    u16* __restrict__ yh, u16* __restrict__ yl,
    float* __restrict__ hstate, int CL, int first) {
  __shared__ float dts[2][64][16], xcs[2][64][16], Bs[2][64][16], Cs[2][64][16], zs[2][64][16];
  int b = blockIdx.y;
  int d0 = blockIdx.x * 16;
  int t = threadIdx.x;
  int g = t >> 4, n = t & 15;
  int d = d0 + g;
  float An = -__expf(A_log[d * 16 + n]);
  float Dd = D_skip[d];
  size_t hidx = ((size_t)b * 512 + d) * 16 + n;
  float h = first ? 0.f : hstate[hidx];
  int sr = t >> 2, sc = (t & 3) * 4;
  size_t base = (size_t)b * CL;
  int nt = CL >> 6;
  {
    size_t row = base + sr;
    *(float4*)&dts[0][sr][sc] = *(const float4*)&dtv[row * 512 + d0 + sc];
    *(float4*)&xcs[0][sr][sc] = *(const float4*)&xc [row * 512 + d0 + sc];
    *(float4*)&zs [0][sr][sc] = *(const float4*)&z  [row * 512 + d0 + sc];
    *(float4*)&Bs [0][sr][sc] = *(const float4*)&xdbl[row * 64 + 16 + sc];
    *(float4*)&Cs [0][sr][sc] = *(const float4*)&xdbl[row * 64 + 32 + sc];
  }
  __syncthreads();
  int buf = 0;
  for (int tile = 0; tile < nt; ++tile) {
    float4 p0, p1, p2, p3, p4;
    bool more = (tile + 1 < nt);
    if (more) {
      size_t row = base + (size_t)(tile + 1) * 64 + sr;
      p0 = *(const float4*)&dtv[row * 512 + d0 + sc];
      p1 = *(const float4*)&xc [row * 512 + d0 + sc];
      p2 = *(const float4*)&z  [row * 512 + d0 + sc];
      p3 = *(const float4*)&xdbl[row * 64 + 16 + sc];
      p4 = *(const float4*)&xdbl[row * 64 + 32 + sc];
    }
    size_t grow = base + (size_t)tile * 64;
    #pragma unroll 4
    for (int l = 0; l < 64; ++l) {
      float dt_ = dts[buf][l][g];
      float xv  = xcs[buf][l][g];
      float Bn  = Bs[buf][l][n];
      float Cn  = Cs[buf][l][n];
      float dA  = __expf(dt_ * An);
      h = fmaf(h, dA, dt_ * xv * Bn);
      float acc = h * Cn;
      acc += __shfl_xor(acc, 1, 64);
      acc += __shfl_xor(acc, 2, 64);
      acc += __shfl_xor(acc, 4, 64);
      acc += __shfl_xor(acc, 8, 64);
      if (n == 0) {
        float zv = zs[buf][l][g];
        float sig = 1.f / (1.f + __expf(-zv));
        float val = fmaf(xv, Dd, acc) * (zv * sig);
        u16 hh, ll; bsplit(val, hh, ll);
        size_t o = (grow + l) * 512 + d;
        yh[o] = hh; yl[o] = ll;
      }
    }
    if (more) {
      *(float4*)&dts[buf ^ 1][sr][sc] = p0;
      *(float4*)&xcs[buf ^ 1][sr][sc] = p1;
      *(float4*)&zs [buf ^ 1][sr][sc] = p2;
      *(float4*)&Bs [buf ^ 1][sr][sc] = p3;
      *(float4*)&Cs [buf ^ 1][sr][sc] = p4;
    }
    __syncthreads();
    buf ^= 1;
  }
  hstate[hidx] = h;
}

// ---------------- scatter chunk rows into global emb ----------------
template<bool ADD>
__global__ __launch_bounds__(256) void scatter_emb(
    const float* __restrict__ E, float* __restrict__ emb, int l0, int lg) {
  int rb = blockIdx.x;
  int t = threadIdx.x;
  size_t grow = ((size_t)(rb >> lg) << 12) + l0 + (rb & ((1 << lg) - 1));
  float v = E[(size_t)rb * 256 + t];
  if (ADD) emb[grow * 256 + t] += v;
  else     emb[grow * 256 + t] = v;
}

// ---------------- final rmsnorm fused with pooling partials ----------------
__global__ __launch_bounds__(256) void normpool_partial(
    const float* __restrict__ emb, const float* __restrict__ nf,
    float* __restrict__ part) {
  int b = blockIdx.x, ch = blockIdx.y, t = threadIdx.x;
  __shared__ float wsum[4];
  float acc = 0.f;
  for (int l = ch * 128; l < ch * 128 + 128; ++l) {
    size_t row = (size_t)b * 4096 + l;
    float v = emb[row * 256 + t];
    float sq = v * v;
    for (int m = 1; m < 64; m <<= 1) sq += __shfl_xor(sq, m, 64);
    if ((t & 63) == 0) wsum[t >> 6] = sq;
    __syncthreads();
    float tot = wsum[0] + wsum[1] + wsum[2] + wsum[3];
    __syncthreads();
    acc += v * rsqrtf(tot * (1.f / 256.f) + 1e-5f);
  }
  part[((size_t)b * 32 + ch) * 256 + t] = acc * nf[t];
}

__global__ __launch_bounds__(256) void pool_reduce_kernel(
    const float* __restrict__ part, float* __restrict__ pooled) {
  int b = blockIdx.x, t = threadIdx.x;
  float s = 0.f;
  for (int c = 0; c < 32; ++c) s += part[((size_t)b * 32 + c) * 256 + t];
  pooled[b * 256 + t] = s * (1.f / 4096.f);
}

__global__ __launch_bounds__(128) void head_kernel(
    const float* __restrict__ pooled, const float* __restrict__ hw,
    const float* __restrict__ hb, float* __restrict__ out) {
  int t = threadIdx.x;
  if (t < 80) {
    int b = t / 10, c = t % 10;
    float a = hb[c];
    for (int dd = 0; dd < 256; ++dd) a = fmaf(pooled[b * 256 + dd], hw[c * 256 + dd], a);
    out[t] = a;
  }
}

extern "C" void kernel_launch(void* const* d_in, const int* in_sizes, int n_in,
                              void* d_out, int out_size, void* d_ws, size_t ws_size,
                              hipStream_t stream) {
  const float* x         = (const float*)d_in[0];
  const int*   perm      = (const int*)d_in[1];
  const float* patch_w   = (const float*)d_in[2];
  const float* patch_b   = (const float*)d_in[3];
  const float* norm_w    = (const float*)d_in[4];
  const float* in_proj_w = (const float*)d_in[5];
  const float* conv_w    = (const float*)d_in[6];
  const float* conv_b    = (const float*)d_in[7];
  const float* x_proj_w  = (const float*)d_in[8];
  const float* dt_w      = (const float*)d_in[9];
  const float* dt_b      = (const float*)d_in[10];
  const float* A_log     = (const float*)d_in[11];
  const float* D_skip    = (const float*)d_in[12];
  const float* out_w     = (const float*)d_in[13];
  const float* norm_f    = (const float*)d_in[14];
  const float* head_w    = (const float*)d_in[15];
  const float* head_b    = (const float*)d_in[16];
  float* outp = (float*)d_out;

  const size_t M = (size_t)BATCH * SEQL;  // 32768
  float* ws     = (float*)d_ws;
  float* emb    = ws;                       // M*256
  float* hstate = emb + M * 256;            // 65536
  float* cstate = hstate + 65536;           // 12288
  float* part   = cstate + 12288;           // 65536
  float* pooled = part + 65536;             // 2048
  u16* wi_h = (u16*)(pooled + 2048);        // 1024*256
  u16* wi_l = wi_h + 262144;
  u16* wo_h = wi_l + 262144;                // 256*512
  u16* wo_l = wo_h + 131072;
  u16* wx_h = wo_l + 131072;                // 64*512
  u16* wx_l = wx_h + 32768;
  u16* wp_h = wx_l + 32768;                 // 256*192
  u16* wp_l = wp_h + 49152;
  float* cbase = (float*)(wp_l + 49152);

  size_t fixedF = (size_t)(cbase - ws);
  int CL = 4096;
  while (CL > 64) {
    size_t need = (fixedF + (size_t)8 * CL * 3392) * sizeof(float);
    if (need <= ws_size) break;
    CL >>= 1;
  }
  int lg = 31 - __builtin_clz((unsigned)CL);
  int nch = 4096 / CL;
  int CR = 8 * CL;

  u16*   u_h  = (u16*)cbase;                 // CR*256
  u16*   u_l  = u_h + (size_t)CR * 256;
  float* xraw = (float*)(u_l + (size_t)CR * 256);  // CR*512
  float* z    = xraw + (size_t)CR * 512;     // CR*512
  float* xc   = z + (size_t)CR * 512;        // CR*512
  u16*   xc_h = (u16*)(xc + (size_t)CR * 512);     // CR*512
  u16*   xc_l = xc_h + (size_t)CR * 512;
  float* xdbl = (float*)(xc_l + (size_t)CR * 512); // CR*64
  float* dtvb = xdbl + (size_t)CR * 64;      // CR*512
  u16*   y_h  = (u16*)(dtvb + (size_t)CR * 512);   // CR*512
  u16*   y_l  = y_h + (size_t)CR * 512;
  u16*   P_h  = (u16*)xraw;                  // CR*192 (alias)
  u16*   P_l  = P_h + (size_t)CR * 192;
  float* E    = z;                           // CR*256 (alias)

  // ---- patch embed ----
  convert_split<<<48, 256, 0, stream>>>(patch_w, wp_h, wp_l, 49152);
  for (int c = 0; c < nch; ++c) {
    int l0 = c * CL;
    im2col_chunk<<<CR * 192 / 256, 256, 0, stream>>>(x, perm, P_h, P_l, l0, lg);
    gemm_bf3<true><<<dim3(4, CR / 64), 256, 0, stream>>>(P_h, P_l, wp_h, wp_l, patch_b, E, 256, 192);
    scatter_emb<false><<<CR, 256, 0, stream>>>(E, emb, l0, lg);
  }

  // ---- layers ----
  for (int layer = 0; layer < 4; ++layer) {
    convert_split<<<256, 256, 0, stream>>>(in_proj_w + (size_t)layer * 262144, wi_h, wi_l, 262144);
    convert_split<<<128, 256, 0, stream>>>(out_w + (size_t)layer * 131072, wo_h, wo_l, 131072);
    padxp_convert<<<32, 256, 0, stream>>>(x_proj_w + (size_t)layer * 48 * 512, wx_h, wx_l);
    for (int c = 0; c < nch; ++c) {
      int l0 = c * CL;
      rmsnorm_chunk<<<CR, 256, 0, stream>>>(emb, norm_w + layer * 256, u_h, u_l, l0, lg);
      gemm_bf3<false><<<dim3(8, CR / 64), 256, 0, stream>>>(
          u_h, u_l, wi_h, wi_l, nullptr, xraw, 512, 256);
      gemm_bf3<false><<<dim3(8, CR / 64), 256, 0, stream>>>(
          u_h, u_l, wi_h + 512 * 256, wi_l + 512 * 256, nullptr, z, 512, 256);
      conv_chunk<<<CR * 512 / 256, 256, 0, stream>>>(
          xraw, cstate, conv_w + layer * 2048, conv_b + layer * 512, xc, xc_h, xc_l, l0, lg);
      save_hist<<<48, 256, 0, stream>>>(xraw, cstate, lg);
      gemm_bf3<false><<<dim3(1, CR / 64), 256, 0, stream>>>(
          xc_h, xc_l, wx_h, wx_l, nullptr, xdbl, 64, 512);
      dt_chunk<<<CR * 512 / 256, 256, 0, stream>>>(
          xdbl, dt_w + layer * 8192, dt_b + layer * 512, dtvb);
      scan_chunk<<<dim3(32, 8), 256, 0, stream>>>(
          dtvb, xdbl, xc, z, A_log + layer * 8192, D_skip + layer * 512,
          y_h, y_l, hstate, CL, c == 0 ? 1 : 0);
      gemm_bf3<false><<<dim3(4, CR / 64), 256, 0, stream>>>(
          y_h, y_l, wo_h, wo_l, nullptr, E, 256, 512);
      scatter_emb<true><<<CR, 256, 0, stream>>>(E, emb, l0, lg);
    }
  }

  // ---- final norm + pool + head ----
  normpool_partial<<<dim3(8, 32), 256, 0, stream>>>(emb, norm_f, part);
  pool_reduce_kernel<<<8, 256, 0, stream>>>(part, pooled);
  head_kernel<<<1, 128, 0, stream>>>(pooled, head_w, head_b, outp);
}

// Round 4
// 4608.374 us; speedup vs baseline: 3.2200x; 1.3380x over previous
//
#include <hip/hip_runtime.h>
#include <hip/hip_bf16.h>
#include <math.h>

#define BATCH 8
#define SEQL  4096

typedef unsigned short u16;
typedef short bf16x8 __attribute__((ext_vector_type(8)));
typedef float f32x4 __attribute__((ext_vector_type(4)));

__device__ __forceinline__ u16 bfr(float a) {
  unsigned u = __float_as_uint(a);
  return (u16)((u + 0x7FFFu + ((u >> 16) & 1u)) >> 16);
}
__device__ __forceinline__ void bsplit(float a, u16& h, u16& l) {
  u16 hb = bfr(a);
  float hf = __uint_as_float((unsigned)hb << 16);
  h = hb;
  l = bfr(a - hf);
}

// ---------------- generic fp32 -> bf16 hi/lo split ----------------
__global__ __launch_bounds__(256) void convert_split(
    const float* __restrict__ in, u16* __restrict__ hi, u16* __restrict__ lo, int n) {
  int i4 = (blockIdx.x * 256 + threadIdx.x) * 4;
  if (i4 >= n) return;
  float4 v = *(const float4*)(in + i4);
  u16 h0,l0,h1,l1,h2,l2,h3,l3;
  bsplit(v.x,h0,l0); bsplit(v.y,h1,l1); bsplit(v.z,h2,l2); bsplit(v.w,h3,l3);
  hi[i4]=h0; hi[i4+1]=h1; hi[i4+2]=h2; hi[i4+3]=h3;
  lo[i4]=l0; lo[i4+1]=l1; lo[i4+2]=l2; lo[i4+3]=l3;
}

__global__ __launch_bounds__(256) void padxp_convert(
    const float* __restrict__ xpw, u16* __restrict__ hi, u16* __restrict__ lo) {
  int i4 = (blockIdx.x * 256 + threadIdx.x) * 4;   // over 64*512
  if (i4 >= 64 * 512) return;
  int row = i4 >> 9;
  float4 v = row < 48 ? *(const float4*)(xpw + i4) : make_float4(0.f,0.f,0.f,0.f);
  u16 h0,l0,h1,l1,h2,l2,h3,l3;
  bsplit(v.x,h0,l0); bsplit(v.y,h1,l1); bsplit(v.z,h2,l2); bsplit(v.w,h3,l3);
  hi[i4]=h0; hi[i4+1]=h1; hi[i4+2]=h2; hi[i4+3]=h3;
  lo[i4]=l0; lo[i4+1]=l1; lo[i4+2]=l2; lo[i4+3]=l3;
}

// ---------------- im2col: patchify + hilbert permute -> bf16 hi/lo ----------------
__global__ __launch_bounds__(256) void im2col_chunk(
    const float* __restrict__ x, const int* __restrict__ perm,
    u16* __restrict__ Ph, u16* __restrict__ Pl, int l0, int lg) {
  int idx = blockIdx.x * 256 + threadIdx.x;   // CR*192
  int k = idx % 192;
  int rb = idx / 192;
  int b = rb >> lg;
  int l = l0 + (rb & ((1 << lg) - 1));
  int j = perm[l];
  int py = j >> 6, px = j & 63;
  int c = k / 64;
  int uu = (k & 63) >> 3;
  int v = k & 7;
  float a = x[(((size_t)b * 3 + c) * 512 + (size_t)(py * 8 + uu)) * 512 + px * 8 + v];
  u16 h, lw; bsplit(a, h, lw);
  Ph[(size_t)rb * 192 + k] = h;
  Pl[(size_t)rb * 192 + k] = lw;
}

// ---------------- MFMA GEMM, 3-term bf16 split, fp32 accumulate ----------------
// C[M,N] (+)= A[M,K] * W[N,K]^T (+bias). BM=BN=64, BK=32, 256 thr (2x2 waves).
template<bool BIAS, bool ACC>
__global__ __launch_bounds__(256) void gemm_bf3(
    const u16* __restrict__ Ah, const u16* __restrict__ Al,
    const u16* __restrict__ Wh, const u16* __restrict__ Wl,
    const float* __restrict__ bias, float* __restrict__ C,
    int N, int K) {
  __shared__ u16 As_h[64 * 32], As_l[64 * 32], Ws_h[64 * 32], Ws_l[64 * 32];
  const int bm = blockIdx.y * 64, bn = blockIdx.x * 64;
  const int t = threadIdx.x;
  const int r = t >> 2, kq = (t & 3) * 8;
  const int lane = t & 63, w = t >> 6;
  const int wr = w >> 1, wc = w & 1;
  const int l15 = lane & 15, kg = lane >> 4;

  const int soff = r * 64 + ((kq * 2) ^ (((r >> 1) & 3) << 4));
  const int ar0 = wr * 32 + l15, ar1 = ar0 + 16;
  const int br0 = wc * 32 + l15, br1 = br0 + 16;
  const int fa0 = ar0 * 64 + ((kg * 16) ^ (((ar0 >> 1) & 3) << 4));
  const int fa1 = ar1 * 64 + ((kg * 16) ^ (((ar1 >> 1) & 3) << 4));
  const int fb0 = br0 * 64 + ((kg * 16) ^ (((br0 >> 1) & 3) << 4));
  const int fb1 = br1 * 64 + ((kg * 16) ^ (((br1 >> 1) & 3) << 4));

  f32x4 acc00 = {0.f,0.f,0.f,0.f}, acc01 = {0.f,0.f,0.f,0.f};
  f32x4 acc10 = {0.f,0.f,0.f,0.f}, acc11 = {0.f,0.f,0.f,0.f};

  const size_t arow = (size_t)(bm + r) * K;
  const size_t wrow = (size_t)(bn + r) * K;

  for (int k0 = 0; k0 < K; k0 += 32) {
    uint4 va_h = *(const uint4*)(Ah + arow + k0 + kq);
    uint4 va_l = *(const uint4*)(Al + arow + k0 + kq);
    uint4 vw_h = *(const uint4*)(Wh + wrow + k0 + kq);
    uint4 vw_l = *(const uint4*)(Wl + wrow + k0 + kq);
    __syncthreads();
    *(uint4*)((char*)As_h + soff) = va_h;
    *(uint4*)((char*)As_l + soff) = va_l;
    *(uint4*)((char*)Ws_h + soff) = vw_h;
    *(uint4*)((char*)Ws_l + soff) = vw_l;
    __syncthreads();
    bf16x8 ah0 = *(const bf16x8*)((const char*)As_h + fa0);
    bf16x8 ah1 = *(const bf16x8*)((const char*)As_h + fa1);
    bf16x8 al0 = *(const bf16x8*)((const char*)As_l + fa0);
    bf16x8 al1 = *(const bf16x8*)((const char*)As_l + fa1);
    bf16x8 bh0 = *(const bf16x8*)((const char*)Ws_h + fb0);
    bf16x8 bh1 = *(const bf16x8*)((const char*)Ws_h + fb1);
    bf16x8 bl0 = *(const bf16x8*)((const char*)Ws_l + fb0);
    bf16x8 bl1 = *(const bf16x8*)((const char*)Ws_l + fb1);
    acc00 = __builtin_amdgcn_mfma_f32_16x16x32_bf16(ah0, bh0, acc00, 0, 0, 0);
    acc01 = __builtin_amdgcn_mfma_f32_16x16x32_bf16(ah0, bh1, acc01, 0, 0, 0);
    acc10 = __builtin_amdgcn_mfma_f32_16x16x32_bf16(ah1, bh0, acc10, 0, 0, 0);
    acc11 = __builtin_amdgcn_mfma_f32_16x16x32_bf16(ah1, bh1, acc11, 0, 0, 0);
    acc00 = __builtin_amdgcn_mfma_f32_16x16x32_bf16(ah0, bl0, acc00, 0, 0, 0);
    acc01 = __builtin_amdgcn_mfma_f32_16x16x32_bf16(ah0, bl1, acc01, 0, 0, 0);
    acc10 = __builtin_amdgcn_mfma_f32_16x16x32_bf16(ah1, bl0, acc10, 0, 0, 0);
    acc11 = __builtin_amdgcn_mfma_f32_16x16x32_bf16(ah1, bl1, acc11, 0, 0, 0);
    acc00 = __builtin_amdgcn_mfma_f32_16x16x32_bf16(al0, bh0, acc00, 0, 0, 0);
    acc01 = __builtin_amdgcn_mfma_f32_16x16x32_bf16(al0, bh1, acc01, 0, 0, 0);
    acc10 = __builtin_amdgcn_mfma_f32_16x16x32_bf16(al1, bh0, acc10, 0, 0, 0);
    acc11 = __builtin_amdgcn_mfma_f32_16x16x32_bf16(al1, bh1, acc11, 0, 0, 0);
  }

  const int rowb = bm + wr * 32 + kg * 4;
  const int colb = bn + wc * 32 + l15;
  float bi0 = 0.f, bi1 = 0.f;
  if (BIAS) { bi0 = bias[colb]; bi1 = bias[colb + 16]; }
  #pragma unroll
  for (int q = 0; q < 4; ++q) {
    size_t o0 = (size_t)(rowb + q) * N + colb;
    size_t o1 = (size_t)(rowb + 16 + q) * N + colb;
    if (ACC) {
      C[o0]      += acc00[q]; C[o0 + 16] += acc01[q];
      C[o1]      += acc10[q]; C[o1 + 16] += acc11[q];
    } else {
      C[o0]      = acc00[q] + bi0; C[o0 + 16] = acc01[q] + bi1;
      C[o1]      = acc10[q] + bi0; C[o1 + 16] = acc11[q] + bi1;
    }
  }
}

// ---------------- RMSNorm: one wave per row, float4 ----------------
__global__ __launch_bounds__(256) void rmsnorm_rows(
    const float* __restrict__ emb, const float* __restrict__ w,
    u16* __restrict__ uh, u16* __restrict__ ul, int l0, int lg) {
  int wv = threadIdx.x >> 6, lane = threadIdx.x & 63;
  int rb = blockIdx.x * 4 + wv;
  size_t grow = ((size_t)(rb >> lg) << 12) + l0 + (rb & ((1 << lg) - 1));
  float4 v = *(const float4*)&emb[grow * 256 + lane * 4];
  float sq = v.x*v.x + v.y*v.y + v.z*v.z + v.w*v.w;
  #pragma unroll
  for (int m = 1; m < 64; m <<= 1) sq += __shfl_xor(sq, m, 64);
  float r = rsqrtf(sq * (1.f / 256.f) + 1e-5f);
  float4 wt = *(const float4*)&w[lane * 4];
  ushort4 hh, ll; u16 a, b;
  bsplit(v.x * r * wt.x, a, b); hh.x = a; ll.x = b;
  bsplit(v.y * r * wt.y, a, b); hh.y = a; ll.y = b;
  bsplit(v.z * r * wt.z, a, b); hh.z = a; ll.z = b;
  bsplit(v.w * r * wt.w, a, b); hh.w = a; ll.w = b;
  *(ushort4*)&uh[(size_t)rb * 256 + lane * 4] = hh;
  *(ushort4*)&ul[(size_t)rb * 256 + lane * 4] = ll;
}

// ---------------- causal depthwise conv + silu; fp32 + bf16 hi/lo ----------------
__global__ __launch_bounds__(256) void conv_chunk(
    const float* __restrict__ xraw, const float* __restrict__ cstate,
    const float* __restrict__ cw, const float* __restrict__ cb,
    float* __restrict__ xc, u16* __restrict__ xch, u16* __restrict__ xcl,
    int l0, int lg) {
  int idx = blockIdx.x * 256 + threadIdx.x;   // CR*512
  int d = idx & 511;
  int rb = idx >> 9;
  int b = rb >> lg;
  int l = l0 + (rb & ((1 << lg) - 1));
  float acc = cb[d];
  #pragma unroll
  for (int k = 0; k < 4; ++k) {
    int ls = l - 3 + k;
    if (ls >= 0) {
      int lo = ls - l0;
      float xv;
      if (lo >= 0) xv = xraw[((size_t)(b << lg) + lo) * 512 + d];
      else         xv = cstate[((size_t)b * 3 + (lo + 3)) * 512 + d];
      acc = fmaf(xv, cw[d * 4 + k], acc);
    }
  }
  float sig = 1.f / (1.f + __expf(-acc));
  float val = acc * sig;
  xc[(size_t)rb * 512 + d] = val;
  u16 h, lw; bsplit(val, h, lw);
  xch[(size_t)rb * 512 + d] = h;
  xcl[(size_t)rb * 512 + d] = lw;
}

__global__ __launch_bounds__(256) void save_hist(
    const float* __restrict__ xraw, float* __restrict__ cstate, int lg) {
  int idx = blockIdx.x * 256 + threadIdx.x;   // 8*3*512
  int d = idx & 511;
  int r = (idx >> 9) % 3;
  int b = (idx >> 9) / 3;
  int CL = 1 << lg;
  cstate[idx] = xraw[((size_t)(b << lg) + CL - 3 + r) * 512 + d];
}

// ---------------- dt = softplus(xdbl[:, :16] @ dt_w^T + dt_b) ----------------
__global__ __launch_bounds__(256) void dt_chunk(
    const float* __restrict__ xdbl, const float* __restrict__ dtw,
    const float* __restrict__ dtbias, float* __restrict__ dtv) {
  int idx = blockIdx.x * 256 + threadIdx.x;   // CR*512
  int d = idx & 511;
  int row = idx >> 9;
  const float* xd = xdbl + (size_t)row * 64;
  float a = dtbias[d];
  #pragma unroll
  for (int r = 0; r < 16; ++r) a = fmaf(xd[r], dtw[d * 16 + r], a);
  dtv[idx] = (a > 20.f) ? a : log1pf(__expf(a));
}

// ---------------- segmented scan pass 1: local scan from 0, emit h_end + sum(dt) ----------------
__global__ __launch_bounds__(256) void seg_state(
    const float* __restrict__ dtv, const float* __restrict__ xc,
    const float* __restrict__ xdbl, const float* __restrict__ A_log,
    float* __restrict__ h_end, float* __restrict__ sdt_out, int CL, int TL) {
  int dblk = blockIdx.x, b = blockIdx.y, s = blockIdx.z;
  int g = threadIdx.x >> 4, n = threadIdx.x & 15;
  int d = dblk * 16 + g;
  float An = -__expf(A_log[d * 16 + n]);
  float h = 0.f, sdt = 0.f;
  size_t row = (size_t)b * CL + (size_t)s * TL;
  for (int l = 0; l < TL; ++l, ++row) {
    float dt_ = dtv[row * 512 + d];
    float xv  = xc [row * 512 + d];
    float Bn  = xdbl[row * 64 + 16 + n];
    float dA  = __expf(dt_ * An);
    h = fmaf(h, dA, dt_ * xv * Bn);
    sdt += dt_;
  }
  size_t o = (((size_t)s * 8 + b) * 512 + d) * 16 + n;
  h_end[o] = h;
  if (n == 0) sdt_out[((size_t)s * 8 + b) * 512 + d] = sdt;
}

// ---------------- segmented scan pass 2: serial combine over segments ----------------
__global__ __launch_bounds__(256) void seg_combine(
    const float* __restrict__ h_end, const float* __restrict__ sdt,
    const float* __restrict__ A_log, float* __restrict__ h_in,
    float* __restrict__ hstate, int S, int first) {
  int idx = blockIdx.x * 256 + threadIdx.x;  // 65536 = 8*512*16
  int n = idx & 15, d = (idx >> 4) & 511, b = idx >> 13;
  float An = -__expf(A_log[d * 16 + n]);
  size_t hidx = ((size_t)b * 512 + d) * 16 + n;
  float acc = first ? 0.f : hstate[hidx];
  for (int s = 0; s < S; ++s) {
    size_t o = (((size_t)s * 8 + b) * 512 + d) * 16 + n;
    h_in[o] = acc;
    float P = __expf(An * sdt[((size_t)s * 8 + b) * 512 + d]);
    acc = fmaf(acc, P, h_end[o]);
  }
  hstate[hidx] = acc;
}

// ---------------- segmented scan pass 3: full scan from h_in, write gated y ----------------
__global__ __launch_bounds__(256) void seg_scan(
    const float* __restrict__ dtv, const float* __restrict__ xc,
    const float* __restrict__ xdbl, const float* __restrict__ z,
    const float* __restrict__ A_log, const float* __restrict__ D_skip,
    const float* __restrict__ h_in, u16* __restrict__ yh, u16* __restrict__ yl,
    int CL, int TL) {
  int dblk = blockIdx.x, b = blockIdx.y, s = blockIdx.z;
  int g = threadIdx.x >> 4, n = threadIdx.x & 15;
  int d = dblk * 16 + g;
  float An = -__expf(A_log[d * 16 + n]);
  float Dd = D_skip[d];
  float h = h_in[(((size_t)s * 8 + b) * 512 + d) * 16 + n];
  size_t row = (size_t)b * CL + (size_t)s * TL;
  for (int l = 0; l < TL; ++l, ++row) {
    float dt_ = dtv[row * 512 + d];
    float xv  = xc [row * 512 + d];
    float Bn  = xdbl[row * 64 + 16 + n];
    float Cn  = xdbl[row * 64 + 32 + n];
    float dA  = __expf(dt_ * An);
    h = fmaf(h, dA, dt_ * xv * Bn);
    float acc = h * Cn;
    acc += __shfl_xor(acc, 1, 64);
    acc += __shfl_xor(acc, 2, 64);
    acc += __shfl_xor(acc, 4, 64);
    acc += __shfl_xor(acc, 8, 64);
    if (n == 0) {
      float zv = z[row * 512 + d];
      float sig = 1.f / (1.f + __expf(-zv));
      float val = fmaf(xv, Dd, acc) * (zv * sig);
      u16 hh, ll; bsplit(val, hh, ll);
      size_t o = row * 512 + d;
      yh[o] = hh; yl[o] = ll;
    }
  }
}

// ---------------- scatter chunk rows into global emb (fallback, wave-per-row) ----------------
template<bool ADD>
__global__ __launch_bounds__(256) void scatter_rows(
    const float* __restrict__ E, float* __restrict__ emb, int l0, int lg) {
  int wv = threadIdx.x >> 6, lane = threadIdx.x & 63;
  int rb = blockIdx.x * 4 + wv;
  size_t grow = ((size_t)(rb >> lg) << 12) + l0 + (rb & ((1 << lg) - 1));
  float4 v = *(const float4*)&E[(size_t)rb * 256 + lane * 4];
  float* dst = &emb[grow * 256 + lane * 4];
  if (ADD) {
    float4 o = *(const float4*)dst;
    v.x += o.x; v.y += o.y; v.z += o.z; v.w += o.w;
  }
  *(float4*)dst = v;
}

// ---------------- final rmsnorm fused with pooling partials ----------------
__global__ __launch_bounds__(256) void normpool_partial(
    const float* __restrict__ emb, const float* __restrict__ nf,
    float* __restrict__ part) {
  int b = blockIdx.x, ch = blockIdx.y, t = threadIdx.x;
  __shared__ float wsum[4];
  float acc = 0.f;
  for (int l = ch * 128; l < ch * 128 + 128; ++l) {
    size_t row = (size_t)b * 4096 + l;
    float v = emb[row * 256 + t];
    float sq = v * v;
    for (int m = 1; m < 64; m <<= 1) sq += __shfl_xor(sq, m, 64);
    if ((t & 63) == 0) wsum[t >> 6] = sq;
    __syncthreads();
    float tot = wsum[0] + wsum[1] + wsum[2] + wsum[3];
    __syncthreads();
    acc += v * rsqrtf(tot * (1.f / 256.f) + 1e-5f);
  }
  part[((size_t)b * 32 + ch) * 256 + t] = acc * nf[t];
}

__global__ __launch_bounds__(256) void pool_reduce_kernel(
    const float* __restrict__ part, float* __restrict__ pooled) {
  int b = blockIdx.x, t = threadIdx.x;
  float s = 0.f;
  for (int c = 0; c < 32; ++c) s += part[((size_t)b * 32 + c) * 256 + t];
  pooled[b * 256 + t] = s * (1.f / 4096.f);
}

__global__ __launch_bounds__(128) void head_kernel(
    const float* __restrict__ pooled, const float* __restrict__ hw,
    const float* __restrict__ hb, float* __restrict__ out) {
  int t = threadIdx.x;
  if (t < 80) {
    int b = t / 10, c = t % 10;
    float a = hb[c];
    for (int dd = 0; dd < 256; ++dd) a = fmaf(pooled[b * 256 + dd], hw[c * 256 + dd], a);
    out[t] = a;
  }
}

extern "C" void kernel_launch(void* const* d_in, const int* in_sizes, int n_in,
                              void* d_out, int out_size, void* d_ws, size_t ws_size,
                              hipStream_t stream) {
  const float* x         = (const float*)d_in[0];
  const int*   perm      = (const int*)d_in[1];
  const float* patch_w   = (const float*)d_in[2];
  const float* patch_b   = (const float*)d_in[3];
  const float* norm_w    = (const float*)d_in[4];
  const float* in_proj_w = (const float*)d_in[5];
  const float* conv_w    = (const float*)d_in[6];
  const float* conv_b    = (const float*)d_in[7];
  const float* x_proj_w  = (const float*)d_in[8];
  const float* dt_w      = (const float*)d_in[9];
  const float* dt_b      = (const float*)d_in[10];
  const float* A_log     = (const float*)d_in[11];
  const float* D_skip    = (const float*)d_in[12];
  const float* out_w     = (const float*)d_in[13];
  const float* norm_f    = (const float*)d_in[14];
  const float* head_w    = (const float*)d_in[15];
  const float* head_b    = (const float*)d_in[16];
  float* outp = (float*)d_out;

  const size_t M = (size_t)BATCH * SEQL;  // 32768
  float* ws     = (float*)d_ws;
  float* emb    = ws;                       // M*256
  float* hstate = emb + M * 256;            // 65536
  float* cstate = hstate + 65536;           // 12288
  float* part   = cstate + 12288;           // 65536
  float* pooled = part + 65536;             // 2048
  float* h_end  = pooled + 2048;            // 32*65536
  float* h_inb  = h_end + 32 * 65536;       // 32*65536
  float* sdtb   = h_inb + 32 * 65536;       // 32*4096
  u16* wi_h = (u16*)(sdtb + 32 * 4096);     // 1024*256
  u16* wi_l = wi_h + 262144;
  u16* wo_h = wi_l + 262144;                // 256*512
  u16* wo_l = wo_h + 131072;
  u16* wx_h = wo_l + 131072;                // 64*512
  u16* wx_l = wx_h + 32768;
  u16* wp_h = wx_l + 32768;                 // 256*192
  u16* wp_l = wp_h + 49152;
  float* cbase = (float*)(wp_l + 49152);

  size_t fixedF = (size_t)(cbase - ws);
  int CL = 4096;
  while (CL > 64) {
    size_t need = (fixedF + (size_t)8 * CL * 3392) * sizeof(float);
    if (need <= ws_size) break;
    CL >>= 1;
  }
  int lg = 31 - __builtin_clz((unsigned)CL);
  int nch = 4096 / CL;
  int CR = 8 * CL;
  int S = CL >= 128 ? CL / 128 : 1;
  int TL = CL / S;
  bool ident = (nch == 1);

  u16*   u_h  = (u16*)cbase;                 // CR*256
  u16*   u_l  = u_h + (size_t)CR * 256;
  float* xraw = (float*)(u_l + (size_t)CR * 256);  // CR*512
  float* z    = xraw + (size_t)CR * 512;     // CR*512
  float* xc   = z + (size_t)CR * 512;        // CR*512
  u16*   xc_h = (u16*)(xc + (size_t)CR * 512);     // CR*512
  u16*   xc_l = xc_h + (size_t)CR * 512;
  float* xdbl = (float*)(xc_l + (size_t)CR * 512); // CR*64
  float* dtvb = xdbl + (size_t)CR * 64;      // CR*512
  u16*   y_h  = (u16*)(dtvb + (size_t)CR * 512);   // CR*512
  u16*   y_l  = y_h + (size_t)CR * 512;
  u16*   P_h  = (u16*)xraw;                  // CR*192 (alias)
  u16*   P_l  = P_h + (size_t)CR * 192;
  float* E    = z;                           // CR*256 (alias)

  // ---- patch embed ----
  convert_split<<<48, 256, 0, stream>>>(patch_w, wp_h, wp_l, 49152);
  for (int c = 0; c < nch; ++c) {
    int l0 = c * CL;
    im2col_chunk<<<CR * 192 / 256, 256, 0, stream>>>(x, perm, P_h, P_l, l0, lg);
    if (ident) {
      gemm_bf3<true, false><<<dim3(4, CR / 64), 256, 0, stream>>>(
          P_h, P_l, wp_h, wp_l, patch_b, emb, 256, 192);
    } else {
      gemm_bf3<true, false><<<dim3(4, CR / 64), 256, 0, stream>>>(
          P_h, P_l, wp_h, wp_l, patch_b, E, 256, 192);
      scatter_rows<false><<<CR / 4, 256, 0, stream>>>(E, emb, l0, lg);
    }
  }

  // ---- layers ----
  for (int layer = 0; layer < 4; ++layer) {
    convert_split<<<256, 256, 0, stream>>>(in_proj_w + (size_t)layer * 262144, wi_h, wi_l, 262144);
    convert_split<<<128, 256, 0, stream>>>(out_w + (size_t)layer * 131072, wo_h, wo_l, 131072);
    padxp_convert<<<32, 256, 0, stream>>>(x_proj_w + (size_t)layer * 48 * 512, wx_h, wx_l);
    const float* Alog_l = A_log + layer * 8192;
    for (int c = 0; c < nch; ++c) {
      int l0 = c * CL;
      rmsnorm_rows<<<CR / 4, 256, 0, stream>>>(emb, norm_w + layer * 256, u_h, u_l, l0, lg);
      gemm_bf3<false, false><<<dim3(8, CR / 64), 256, 0, stream>>>(
          u_h, u_l, wi_h, wi_l, nullptr, xraw, 512, 256);
      gemm_bf3<false, false><<<dim3(8, CR / 64), 256, 0, stream>>>(
          u_h, u_l, wi_h + 512 * 256, wi_l + 512 * 256, nullptr, z, 512, 256);
      conv_chunk<<<CR * 512 / 256, 256, 0, stream>>>(
          xraw, cstate, conv_w + layer * 2048, conv_b + layer * 512, xc, xc_h, xc_l, l0, lg);
      if (!ident) save_hist<<<48, 256, 0, stream>>>(xraw, cstate, lg);
      gemm_bf3<false, false><<<dim3(1, CR / 64), 256, 0, stream>>>(
          xc_h, xc_l, wx_h, wx_l, nullptr, xdbl, 64, 512);
      dt_chunk<<<CR * 512 / 256, 256, 0, stream>>>(
          xdbl, dt_w + layer * 8192, dt_b + layer * 512, dtvb);
      seg_state<<<dim3(32, 8, S), 256, 0, stream>>>(
          dtvb, xc, xdbl, Alog_l, h_end, sdtb, CL, TL);
      seg_combine<<<256, 256, 0, stream>>>(
          h_end, sdtb, Alog_l, h_inb, hstate, S, c == 0 ? 1 : 0);
      seg_scan<<<dim3(32, 8, S), 256, 0, stream>>>(
          dtvb, xc, xdbl, z, Alog_l, D_skip + layer * 512, h_inb, y_h, y_l, CL, TL);
      if (ident) {
        gemm_bf3<false, true><<<dim3(4, CR / 64), 256, 0, stream>>>(
            y_h, y_l, wo_h, wo_l, nullptr, emb, 256, 512);
      } else {
        gemm_bf3<false, false><<<dim3(4, CR / 64), 256, 0, stream>>>(
            y_h, y_l, wo_h, wo_l, nullptr, E, 256, 512);
        scatter_rows<true><<<CR / 4, 256, 0, stream>>>(E, emb, l0, lg);
      }
    }
  }

  // ---- final norm + pool + head ----
  normpool_partial<<<dim3(8, 32), 256, 0, stream>>>(emb, norm_f, part);
  pool_reduce_kernel<<<8, 256, 0, stream>>>(part, pooled);
  head_kernel<<<1, 128, 0, stream>>>(pooled, head_w, head_b, outp);
}

// Round 5
// 2506.168 us; speedup vs baseline: 5.9210x; 1.8388x over previous
//
#include <hip/hip_runtime.h>
#include <hip/hip_bf16.h>
#include <math.h>

#define BATCH 8
#define SEQL  4096

typedef unsigned short u16;
typedef short bf16x8 __attribute__((ext_vector_type(8)));
typedef float f32x4 __attribute__((ext_vector_type(4)));

__device__ __forceinline__ u16 bfr(float a) {
  unsigned u = __float_as_uint(a);
  return (u16)((u + 0x7FFFu + ((u >> 16) & 1u)) >> 16);
}
__device__ __forceinline__ void bsplit(float a, u16& h, u16& l) {
  u16 hb = bfr(a);
  float hf = __uint_as_float((unsigned)hb << 16);
  h = hb;
  l = bfr(a - hf);
}
__device__ __forceinline__ float bf2f(u16 h) {
  return __uint_as_float((unsigned)h << 16);
}
__device__ __forceinline__ void gload16(const void* g, void* l) {
  typedef __attribute__((address_space(1))) unsigned int gu32;
  typedef __attribute__((address_space(3))) unsigned int lu32;
  __builtin_amdgcn_global_load_lds((const gu32*)g, (lu32*)l, 16, 0, 0);
}

// ---------------- fp32 -> bf16 hi/lo split ----------------
__global__ __launch_bounds__(256) void convert_split(
    const float* __restrict__ in, u16* __restrict__ hi, u16* __restrict__ lo, int n) {
  int i4 = (blockIdx.x * 256 + threadIdx.x) * 4;
  if (i4 >= n) return;
  float4 v = *(const float4*)(in + i4);
  u16 h0,l0,h1,l1,h2,l2,h3,l3;
  bsplit(v.x,h0,l0); bsplit(v.y,h1,l1); bsplit(v.z,h2,l2); bsplit(v.w,h3,l3);
  hi[i4]=h0; hi[i4+1]=h1; hi[i4+2]=h2; hi[i4+3]=h3;
  lo[i4]=l0; lo[i4+1]=l1; lo[i4+2]=l2; lo[i4+3]=l3;
}

// pad x_proj_w (48x512) to 128x512 and split
__global__ __launch_bounds__(256) void padxp_convert(
    const float* __restrict__ xpw, u16* __restrict__ hi, u16* __restrict__ lo) {
  int i4 = (blockIdx.x * 256 + threadIdx.x) * 4;   // over 128*512
  if (i4 >= 128 * 512) return;
  int row = i4 >> 9;
  float4 v = row < 48 ? *(const float4*)(xpw + i4) : make_float4(0.f,0.f,0.f,0.f);
  u16 h0,l0,h1,l1,h2,l2,h3,l3;
  bsplit(v.x,h0,l0); bsplit(v.y,h1,l1); bsplit(v.z,h2,l2); bsplit(v.w,h3,l3);
  hi[i4]=h0; hi[i4+1]=h1; hi[i4+2]=h2; hi[i4+3]=h3;
  lo[i4]=l0; lo[i4+1]=l1; lo[i4+2]=l2; lo[i4+3]=l3;
}

// ---------------- im2col: patchify + hilbert permute -> bf16 hi/lo ----------------
__global__ __launch_bounds__(256) void im2col_chunk(
    const float* __restrict__ x, const int* __restrict__ perm,
    u16* __restrict__ Ph, u16* __restrict__ Pl, int l0, int lg) {
  int idx = blockIdx.x * 256 + threadIdx.x;   // CR*192
  int k = idx % 192;
  int rb = idx / 192;
  int b = rb >> lg;
  int l = l0 + (rb & ((1 << lg) - 1));
  int j = perm[l];
  int py = j >> 6, px = j & 63;
  int c = k / 64;
  int uu = (k & 63) >> 3;
  int v = k & 7;
  float a = x[(((size_t)b * 3 + c) * 512 + (size_t)(py * 8 + uu)) * 512 + px * 8 + v];
  u16 h, lw; bsplit(a, h, lw);
  Ph[(size_t)rb * 192 + k] = h;
  Pl[(size_t)rb * 192 + k] = lw;
}

// ---------------- 128x128 MFMA GEMM, 3-term bf16 split, global_load_lds staging ----
// C[M,N] (+)= A[M,K]*W[N,K]^T (+bias). BK=32, 256 thr (2x2 waves, 64x64 per wave).
template<bool BIAS, bool ACC>
__global__ __launch_bounds__(256) void gemm128_bf3(
    const u16* __restrict__ Ah, const u16* __restrict__ Al,
    const u16* __restrict__ Wh, const u16* __restrict__ Wl,
    const float* __restrict__ bias, float* __restrict__ C,
    int N, int K) {
  __shared__ u16 lds[16384];   // Ah | Al | Wh | Wl, each 128 rows x 32 u16 (4096)
  const int bm = blockIdx.y * 128, bn = blockIdx.x * 128;
  const int t = threadIdx.x;
  const int lane = t & 63, w = t >> 6;
  const int wr = w >> 1, wc = w & 1;
  const int l15 = lane & 15, kg = lane >> 4;

  // staging: wave w stages chunks (w*2, w*2+1), 16 rows each, per array
  const int c0 = w * 2;
  const int srow = lane >> 2;
  const int scol = (lane & 3) * 8;
  const u16* gsrc[8];
  u16* ldst[8];
  {
    size_t ra0 = (size_t)(bm + c0 * 16 + srow) * K + scol;
    size_t ra1 = (size_t)(bm + c0 * 16 + 16 + srow) * K + scol;
    size_t rw0 = (size_t)(bn + c0 * 16 + srow) * K + scol;
    size_t rw1 = (size_t)(bn + c0 * 16 + 16 + srow) * K + scol;
    gsrc[0] = Ah + ra0; gsrc[1] = Ah + ra1;
    gsrc[2] = Al + ra0; gsrc[3] = Al + ra1;
    gsrc[4] = Wh + rw0; gsrc[5] = Wh + rw1;
    gsrc[6] = Wl + rw0; gsrc[7] = Wl + rw1;
    ldst[0] = lds + c0 * 512;          ldst[1] = lds + c0 * 512 + 512;
    ldst[2] = lds + 4096 + c0 * 512;   ldst[3] = lds + 4096 + c0 * 512 + 512;
    ldst[4] = lds + 8192 + c0 * 512;   ldst[5] = lds + 8192 + c0 * 512 + 512;
    ldst[6] = lds + 12288 + c0 * 512;  ldst[7] = lds + 12288 + c0 * 512 + 512;
  }
  const u16* pa_h = lds + (size_t)(wr * 64 + l15) * 32 + kg * 8;
  const u16* pa_l = pa_h + 4096;
  const u16* pb_h = lds + 8192 + (size_t)(wc * 64 + l15) * 32 + kg * 8;
  const u16* pb_l = pb_h + 4096;

  f32x4 acc[4][4] = {};
  for (int k0 = 0; k0 < K; k0 += 32) {
    __syncthreads();   // all waves done reading previous tile
    #pragma unroll
    for (int i = 0; i < 8; ++i) { gload16(gsrc[i], ldst[i]); gsrc[i] += 32; }
    __syncthreads();   // compiler drains vmcnt before barrier -> tile ready
    bf16x8 ah[4], al[4], bh[4], bl[4];
    #pragma unroll
    for (int i = 0; i < 4; ++i) {
      ah[i] = *(const bf16x8*)(pa_h + i * 512);
      al[i] = *(const bf16x8*)(pa_l + i * 512);
      bh[i] = *(const bf16x8*)(pb_h + i * 512);
      bl[i] = *(const bf16x8*)(pb_l + i * 512);
    }
    #pragma unroll
    for (int i = 0; i < 4; ++i)
      #pragma unroll
      for (int j = 0; j < 4; ++j) {
        acc[i][j] = __builtin_amdgcn_mfma_f32_16x16x32_bf16(ah[i], bh[j], acc[i][j], 0, 0, 0);
        acc[i][j] = __builtin_amdgcn_mfma_f32_16x16x32_bf16(ah[i], bl[j], acc[i][j], 0, 0, 0);
        acc[i][j] = __builtin_amdgcn_mfma_f32_16x16x32_bf16(al[i], bh[j], acc[i][j], 0, 0, 0);
      }
  }

  const int row0 = bm + wr * 64 + kg * 4;
  const int col0 = bn + wc * 64 + l15;
  #pragma unroll
  for (int i = 0; i < 4; ++i) {
    #pragma unroll
    for (int q = 0; q < 4; ++q) {
      int row = row0 + i * 16 + q;
      #pragma unroll
      for (int j = 0; j < 4; ++j) {
        int col = col0 + j * 16;
        size_t o = (size_t)row * N + col;
        float v = acc[i][j][q];
        if (BIAS) v += bias[col];
        if (ACC) v += C[o];
        C[o] = v;
      }
    }
  }
}

// ---------------- RMSNorm: one wave per row, float4 ----------------
__global__ __launch_bounds__(256) void rmsnorm_rows(
    const float* __restrict__ emb, const float* __restrict__ w,
    u16* __restrict__ uh, u16* __restrict__ ul, int l0, int lg) {
  int wv = threadIdx.x >> 6, lane = threadIdx.x & 63;
  int rb = blockIdx.x * 4 + wv;
  size_t grow = ((size_t)(rb >> lg) << 12) + l0 + (rb & ((1 << lg) - 1));
  float4 v = *(const float4*)&emb[grow * 256 + lane * 4];
  float sq = v.x*v.x + v.y*v.y + v.z*v.z + v.w*v.w;
  #pragma unroll
  for (int m = 1; m < 64; m <<= 1) sq += __shfl_xor(sq, m, 64);
  float r = rsqrtf(sq * (1.f / 256.f) + 1e-5f);
  float4 wt = *(const float4*)&w[lane * 4];
  ushort4 hh, ll; u16 a, b;
  bsplit(v.x * r * wt.x, a, b); hh.x = a; ll.x = b;
  bsplit(v.y * r * wt.y, a, b); hh.y = a; ll.y = b;
  bsplit(v.z * r * wt.z, a, b); hh.z = a; ll.z = b;
  bsplit(v.w * r * wt.w, a, b); hh.w = a; ll.w = b;
  *(ushort4*)&uh[(size_t)rb * 256 + lane * 4] = hh;
  *(ushort4*)&ul[(size_t)rb * 256 + lane * 4] = ll;
}

// ---------------- causal depthwise conv + silu -> bf16 hi/lo ----------------
__global__ __launch_bounds__(256) void conv_chunk(
    const float* __restrict__ xz, const float* __restrict__ cstate,
    const float* __restrict__ cw, const float* __restrict__ cb,
    u16* __restrict__ xch, u16* __restrict__ xcl, int l0, int lg) {
  int idx = blockIdx.x * 256 + threadIdx.x;   // CR*512
  int d = idx & 511;
  int rb = idx >> 9;
  int b = rb >> lg;
  int l = l0 + (rb & ((1 << lg) - 1));
  float acc = cb[d];
  #pragma unroll
  for (int k = 0; k < 4; ++k) {
    int ls = l - 3 + k;
    if (ls >= 0) {
      int lo = ls - l0;
      float xv;
      if (lo >= 0) xv = xz[((size_t)(b << lg) + lo) * 1024 + d];
      else         xv = cstate[((size_t)b * 3 + (lo + 3)) * 512 + d];
      acc = fmaf(xv, cw[d * 4 + k], acc);
    }
  }
  float sig = 1.f / (1.f + __expf(-acc));
  float val = acc * sig;
  u16 h, lw; bsplit(val, h, lw);
  xch[(size_t)rb * 512 + d] = h;
  xcl[(size_t)rb * 512 + d] = lw;
}

__global__ __launch_bounds__(256) void save_hist(
    const float* __restrict__ xz, float* __restrict__ cstate, int lg) {
  int idx = blockIdx.x * 256 + threadIdx.x;   // 8*3*512
  int d = idx & 511;
  int r = (idx >> 9) % 3;
  int b = (idx >> 9) / 3;
  int CL = 1 << lg;
  cstate[idx] = xz[((size_t)(b << lg) + CL - 3 + r) * 1024 + d];
}

// ---------------- dt = softplus(xdbl[:, :16] @ dt_w^T + dt_b) ----------------
__global__ __launch_bounds__(256) void dt_chunk(
    const float* __restrict__ xdbl, const float* __restrict__ dtw,
    const float* __restrict__ dtbias, float* __restrict__ dtv) {
  int idx = blockIdx.x * 256 + threadIdx.x;   // CR*512
  int d = idx & 511;
  int row = idx >> 9;
  const float* xd = xdbl + (size_t)row * 128;
  float a = dtbias[d];
  #pragma unroll
  for (int r = 0; r < 16; ++r) a = fmaf(xd[r], dtw[d * 16 + r], a);
  dtv[idx] = (a > 20.f) ? a : log1pf(__expf(a));
}

// ---------------- segmented scan pass 1: lane-per-channel, 16 states in regs ----
__global__ __launch_bounds__(256) void seg_state(
    const float* __restrict__ dtv, const u16* __restrict__ xch, const u16* __restrict__ xcl,
    const float* __restrict__ xdbl, const float* __restrict__ A_log,
    float* __restrict__ h_end, float* __restrict__ sdt_out, int CL, int TL) {
  int d = blockIdx.x * 256 + threadIdx.x;
  int b = blockIdx.y, s = blockIdx.z;
  float4 A0 = *(const float4*)(A_log + d * 16);
  float4 A1 = *(const float4*)(A_log + d * 16 + 4);
  float4 A2 = *(const float4*)(A_log + d * 16 + 8);
  float4 A3 = *(const float4*)(A_log + d * 16 + 12);
  float An[16] = {-__expf(A0.x),-__expf(A0.y),-__expf(A0.z),-__expf(A0.w),
                  -__expf(A1.x),-__expf(A1.y),-__expf(A1.z),-__expf(A1.w),
                  -__expf(A2.x),-__expf(A2.y),-__expf(A2.z),-__expf(A2.w),
                  -__expf(A3.x),-__expf(A3.y),-__expf(A3.z),-__expf(A3.w)};
  float h[16];
  #pragma unroll
  for (int n = 0; n < 16; ++n) h[n] = 0.f;
  float sdt = 0.f;
  size_t row = (size_t)b * CL + (size_t)s * TL;
  for (int l = 0; l < TL; ++l, ++row) {
    float dt_ = dtv[row * 512 + d];
    float xv = bf2f(xch[row * 512 + d]) + bf2f(xcl[row * 512 + d]);
    const float* xr = xdbl + row * 128;
    float4 B0 = *(const float4*)(xr + 16);
    float4 B1 = *(const float4*)(xr + 20);
    float4 B2 = *(const float4*)(xr + 24);
    float4 B3 = *(const float4*)(xr + 28);
    float bb[16] = {B0.x,B0.y,B0.z,B0.w,B1.x,B1.y,B1.z,B1.w,
                    B2.x,B2.y,B2.z,B2.w,B3.x,B3.y,B3.z,B3.w};
    float t1 = dt_ * xv;
    #pragma unroll
    for (int n = 0; n < 16; ++n)
      h[n] = fmaf(h[n], __expf(dt_ * An[n]), t1 * bb[n]);
    sdt += dt_;
  }
  size_t o = (((size_t)s * 8 + b) * 512 + d) * 16;
  #pragma unroll
  for (int n = 0; n < 16; n += 4)
    *(float4*)(h_end + o + n) = make_float4(h[n], h[n+1], h[n+2], h[n+3]);
  sdt_out[((size_t)s * 8 + b) * 512 + d] = sdt;
}

// ---------------- pass 2: serial combine (in-place h_end -> h_in) ----------------
__global__ __launch_bounds__(256) void seg_combine(
    float* __restrict__ h_end, const float* __restrict__ sdt,
    const float* __restrict__ A_log, float* __restrict__ hstate, int S, int first) {
  int idx = blockIdx.x * 256 + threadIdx.x;  // 65536 = 8*512*16
  int n = idx & 15, d = (idx >> 4) & 511, b = idx >> 13;
  float An = -__expf(A_log[d * 16 + n]);
  size_t hidx = ((size_t)b * 512 + d) * 16 + n;
  float acc = first ? 0.f : hstate[hidx];
  for (int s = 0; s < S; ++s) {
    size_t o = (((size_t)s * 8 + b) * 512 + d) * 16 + n;
    float he = h_end[o];
    h_end[o] = acc;   // becomes h_in
    float P = __expf(An * sdt[((size_t)s * 8 + b) * 512 + d]);
    acc = fmaf(acc, P, he);
  }
  hstate[hidx] = acc;
}

// ---------------- pass 3: scan from h_in, fused C-reduce + z-gate + y write ------
__global__ __launch_bounds__(256) void seg_scan(
    const float* __restrict__ dtv, const u16* __restrict__ xch, const u16* __restrict__ xcl,
    const float* __restrict__ xdbl, const float* __restrict__ xz,
    const float* __restrict__ A_log, const float* __restrict__ D_skip,
    const float* __restrict__ h_in, u16* __restrict__ yh, u16* __restrict__ yl,
    int CL, int TL) {
  int d = blockIdx.x * 256 + threadIdx.x;
  int b = blockIdx.y, s = blockIdx.z;
  float4 A0 = *(const float4*)(A_log + d * 16);
  float4 A1 = *(const float4*)(A_log + d * 16 + 4);
  float4 A2 = *(const float4*)(A_log + d * 16 + 8);
  float4 A3 = *(const float4*)(A_log + d * 16 + 12);
  float An[16] = {-__expf(A0.x),-__expf(A0.y),-__expf(A0.z),-__expf(A0.w),
                  -__expf(A1.x),-__expf(A1.y),-__expf(A1.z),-__expf(A1.w),
                  -__expf(A2.x),-__expf(A2.y),-__expf(A2.z),-__expf(A2.w),
                  -__expf(A3.x),-__expf(A3.y),-__expf(A3.z),-__expf(A3.w)};
  float Dd = D_skip[d];
  size_t o = (((size_t)s * 8 + b) * 512 + d) * 16;
  float h[16];
  #pragma unroll
  for (int n = 0; n < 16; n += 4) {
    float4 hv = *(const float4*)(h_in + o + n);
    h[n] = hv.x; h[n+1] = hv.y; h[n+2] = hv.z; h[n+3] = hv.w;
  }
  size_t row = (size_t)b * CL + (size_t)s * TL;
  for (int l = 0; l < TL; ++l, ++row) {
    float dt_ = dtv[row * 512 + d];
    float xv = bf2f(xch[row * 512 + d]) + bf2f(xcl[row * 512 + d]);
    const float* xr = xdbl + row * 128;
    float4 B0 = *(const float4*)(xr + 16);
    float4 B1 = *(const float4*)(xr + 20);
    float4 B2 = *(const float4*)(xr + 24);
    float4 B3 = *(const float4*)(xr + 28);
    float4 C0 = *(const float4*)(xr + 32);
    float4 C1 = *(const float4*)(xr + 36);
    float4 C2 = *(const float4*)(xr + 40);
    float4 C3 = *(const float4*)(xr + 44);
    float bb[16] = {B0.x,B0.y,B0.z,B0.w,B1.x,B1.y,B1.z,B1.w,
                    B2.x,B2.y,B2.z,B2.w,B3.x,B3.y,B3.z,B3.w};
    float cc[16] = {C0.x,C0.y,C0.z,C0.w,C1.x,C1.y,C1.z,C1.w,
                    C2.x,C2.y,C2.z,C2.w,C3.x,C3.y,C3.z,C3.w};
    float t1 = dt_ * xv;
    float acc = 0.f;
    #pragma unroll
    for (int n = 0; n < 16; ++n) {
      h[n] = fmaf(h[n], __expf(dt_ * An[n]), t1 * bb[n]);
      acc = fmaf(h[n], cc[n], acc);
    }
    float zv = xz[row * 1024 + 512 + d];
    float sig = 1.f / (1.f + __expf(-zv));
    float val = fmaf(xv, Dd, acc) * (zv * sig);
    u16 hh, ll; bsplit(val, hh, ll);
    yh[row * 512 + d] = hh;
    yl[row * 512 + d] = ll;
  }
}

// ---------------- scatter chunk rows into global emb (fallback) ----------------
template<bool ADD>
__global__ __launch_bounds__(256) void scatter_rows(
    const float* __restrict__ E, float* __restrict__ emb, int l0, int lg) {
  int wv = threadIdx.x >> 6, lane = threadIdx.x & 63;
  int rb = blockIdx.x * 4 + wv;
  size_t grow = ((size_t)(rb >> lg) << 12) + l0 + (rb & ((1 << lg) - 1));
  float4 v = *(const float4*)&E[(size_t)rb * 256 + lane * 4];
  float* dst = &emb[grow * 256 + lane * 4];
  if (ADD) {
    float4 o = *(const float4*)dst;
    v.x += o.x; v.y += o.y; v.z += o.z; v.w += o.w;
  }
  *(float4*)dst = v;
}

// ---------------- final rmsnorm fused with pooling partials ----------------
__global__ __launch_bounds__(256) void normpool_partial(
    const float* __restrict__ emb, const float* __restrict__ nf,
    float* __restrict__ part) {
  int b = blockIdx.x, ch = blockIdx.y, t = threadIdx.x;
  __shared__ float wsum[4];
  float acc = 0.f;
  for (int l = ch * 128; l < ch * 128 + 128; ++l) {
    size_t row = (size_t)b * 4096 + l;
    float v = emb[row * 256 + t];
    float sq = v * v;
    for (int m = 1; m < 64; m <<= 1) sq += __shfl_xor(sq, m, 64);
    if ((t & 63) == 0) wsum[t >> 6] = sq;
    __syncthreads();
    float tot = wsum[0] + wsum[1] + wsum[2] + wsum[3];
    __syncthreads();
    acc += v * rsqrtf(tot * (1.f / 256.f) + 1e-5f);
  }
  part[((size_t)b * 32 + ch) * 256 + t] = acc * nf[t];
}

__global__ __launch_bounds__(256) void pool_reduce_kernel(
    const float* __restrict__ part, float* __restrict__ pooled) {
  int b = blockIdx.x, t = threadIdx.x;
  float s = 0.f;
  for (int c = 0; c < 32; ++c) s += part[((size_t)b * 32 + c) * 256 + t];
  pooled[b * 256 + t] = s * (1.f / 4096.f);
}

__global__ __launch_bounds__(128) void head_kernel(
    const float* __restrict__ pooled, const float* __restrict__ hw,
    const float* __restrict__ hb, float* __restrict__ out) {
  int t = threadIdx.x;
  if (t < 80) {
    int b = t / 10, c = t % 10;
    float a = hb[c];
    for (int dd = 0; dd < 256; ++dd) a = fmaf(pooled[b * 256 + dd], hw[c * 256 + dd], a);
    out[t] = a;
  }
}

extern "C" void kernel_launch(void* const* d_in, const int* in_sizes, int n_in,
                              void* d_out, int out_size, void* d_ws, size_t ws_size,
                              hipStream_t stream) {
  const float* x         = (const float*)d_in[0];
  const int*   perm      = (const int*)d_in[1];
  const float* patch_w   = (const float*)d_in[2];
  const float* patch_b   = (const float*)d_in[3];
  const float* norm_w    = (const float*)d_in[4];
  const float* in_proj_w = (const float*)d_in[5];
  const float* conv_w    = (const float*)d_in[6];
  const float* conv_b    = (const float*)d_in[7];
  const float* x_proj_w  = (const float*)d_in[8];
  const float* dt_w      = (const float*)d_in[9];
  const float* dt_b      = (const float*)d_in[10];
  const float* A_log     = (const float*)d_in[11];
  const float* D_skip    = (const float*)d_in[12];
  const float* out_w     = (const float*)d_in[13];
  const float* norm_f    = (const float*)d_in[14];
  const float* head_w    = (const float*)d_in[15];
  const float* head_b    = (const float*)d_in[16];
  float* outp = (float*)d_out;

  const size_t M = (size_t)BATCH * SEQL;  // 32768
  float* ws     = (float*)d_ws;
  float* emb    = ws;                       // M*256
  float* hstate = emb + M * 256;            // 65536
  float* cstate = hstate + 65536;           // 12288
  float* part   = cstate + 12288;           // 65536
  float* pooled = part + 65536;             // 2048
  float* h_end  = pooled + 2048;            // 64*65536 (h_end -> h_in in place)
  float* sdtb   = h_end + 64 * 65536;       // 64*4096
  u16* wi_h = (u16*)(sdtb + 64 * 4096);     // 1024*256
  u16* wi_l = wi_h + 262144;
  u16* wo_h = wi_l + 262144;                // 256*512
  u16* wo_l = wo_h + 131072;
  u16* wx_h = wo_l + 131072;                // 128*512
  u16* wx_l = wx_h + 65536;
  u16* wp_h = wx_l + 65536;                 // 256*192
  u16* wp_l = wp_h + 49152;
  float* cbase = (float*)(wp_l + 49152);

  size_t fixedF = (size_t)(cbase - ws);
  int CL = 4096;
  while (CL > 64) {
    size_t need = (fixedF + (size_t)8 * CL * 2944) * sizeof(float);
    if (need <= ws_size) break;
    CL >>= 1;
  }
  int lg = 31 - __builtin_clz((unsigned)CL);
  int nch = 4096 / CL;
  int CR = 8 * CL;
  int S = CL / 64, TL = 64;
  bool ident = (nch == 1);

  u16*   u_h  = (u16*)cbase;                        // CR*256
  u16*   u_l  = u_h + (size_t)CR * 256;
  float* xz   = (float*)(u_l + (size_t)CR * 256);   // CR*1024
  u16*   xc_h = (u16*)(xz + (size_t)CR * 1024);     // CR*512
  u16*   xc_l = xc_h + (size_t)CR * 512;
  float* xdbl = (float*)(xc_l + (size_t)CR * 512);  // CR*128
  float* dtvb = xdbl + (size_t)CR * 128;            // CR*512
  u16*   y_h  = (u16*)(dtvb + (size_t)CR * 512);    // CR*512
  u16*   y_l  = y_h + (size_t)CR * 512;
  u16*   P_h  = (u16*)xz;                           // CR*192 (alias, pre-layer only)
  u16*   P_l  = P_h + (size_t)CR * 192;
  float* E    = xz + (size_t)CR * 512;              // CR*256 (alias, no overlap w/ P)

  // ---- patch embed ----
  convert_split<<<48, 256, 0, stream>>>(patch_w, wp_h, wp_l, 49152);
  for (int c = 0; c < nch; ++c) {
    int l0 = c * CL;
    im2col_chunk<<<CR * 192 / 256, 256, 0, stream>>>(x, perm, P_h, P_l, l0, lg);
    if (ident) {
      gemm128_bf3<true, false><<<dim3(2, CR / 128), 256, 0, stream>>>(
          P_h, P_l, wp_h, wp_l, patch_b, emb, 256, 192);
    } else {
      gemm128_bf3<true, false><<<dim3(2, CR / 128), 256, 0, stream>>>(
          P_h, P_l, wp_h, wp_l, patch_b, E, 256, 192);
      scatter_rows<false><<<CR / 4, 256, 0, stream>>>(E, emb, l0, lg);
    }
  }

  // ---- layers ----
  for (int layer = 0; layer < 4; ++layer) {
    convert_split<<<256, 256, 0, stream>>>(in_proj_w + (size_t)layer * 262144, wi_h, wi_l, 262144);
    convert_split<<<128, 256, 0, stream>>>(out_w + (size_t)layer * 131072, wo_h, wo_l, 131072);
    padxp_convert<<<64, 256, 0, stream>>>(x_proj_w + (size_t)layer * 48 * 512, wx_h, wx_l);
    const float* Alog_l = A_log + layer * 8192;
    for (int c = 0; c < nch; ++c) {
      int l0 = c * CL;
      rmsnorm_rows<<<CR / 4, 256, 0, stream>>>(emb, norm_w + layer * 256, u_h, u_l, l0, lg);
      gemm128_bf3<false, false><<<dim3(8, CR / 128), 256, 0, stream>>>(
          u_h, u_l, wi_h, wi_l, nullptr, xz, 1024, 256);
      conv_chunk<<<CR * 512 / 256, 256, 0, stream>>>(
          xz, cstate, conv_w + layer * 2048, conv_b + layer * 512, xc_h, xc_l, l0, lg);
      if (!ident) save_hist<<<48, 256, 0, stream>>>(xz, cstate, lg);
      gemm128_bf3<false, false><<<dim3(1, CR / 128), 256, 0, stream>>>(
          xc_h, xc_l, wx_h, wx_l, nullptr, xdbl, 128, 512);
      dt_chunk<<<CR * 512 / 256, 256, 0, stream>>>(
          xdbl, dt_w + layer * 8192, dt_b + layer * 512, dtvb);
      seg_state<<<dim3(2, 8, S), 256, 0, stream>>>(
          dtvb, xc_h, xc_l, xdbl, Alog_l, h_end, sdtb, CL, TL);
      seg_combine<<<256, 256, 0, stream>>>(
          h_end, sdtb, Alog_l, hstate, S, c == 0 ? 1 : 0);
      seg_scan<<<dim3(2, 8, S), 256, 0, stream>>>(
          dtvb, xc_h, xc_l, xdbl, xz, Alog_l, D_skip + layer * 512, h_end,
          y_h, y_l, CL, TL);
      if (ident) {
        gemm128_bf3<false, true><<<dim3(2, CR / 128), 256, 0, stream>>>(
            y_h, y_l, wo_h, wo_l, nullptr, emb, 256, 512);
      } else {
        gemm128_bf3<false, false><<<dim3(2, CR / 128), 256, 0, stream>>>(
            y_h, y_l, wo_h, wo_l, nullptr, E, 256, 512);
        scatter_rows<true><<<CR / 4, 256, 0, stream>>>(E, emb, l0, lg);
      }
    }
  }

  // ---- final norm + pool + head ----
  normpool_partial<<<dim3(8, 32), 256, 0, stream>>>(emb, norm_f, part);
  pool_reduce_kernel<<<8, 256, 0, stream>>>(part, pooled);
  head_kernel<<<1, 128, 0, stream>>>(pooled, head_w, head_b, outp);
}

// Round 6
// 2384.715 us; speedup vs baseline: 6.2226x; 1.0509x over previous
//
#include <hip/hip_runtime.h>
#include <hip/hip_bf16.h>
#include <math.h>

#define BATCH 8
#define SEQL  4096

typedef unsigned short u16;
typedef short bf16x8 __attribute__((ext_vector_type(8)));
typedef float f32x4 __attribute__((ext_vector_type(4)));

__device__ __forceinline__ u16 bfr(float a) {
  unsigned u = __float_as_uint(a);
  return (u16)((u + 0x7FFFu + ((u >> 16) & 1u)) >> 16);
}
__device__ __forceinline__ void bsplit(float a, u16& h, u16& l) {
  u16 hb = bfr(a);
  float hf = __uint_as_float((unsigned)hb << 16);
  h = hb;
  l = bfr(a - hf);
}
__device__ __forceinline__ float bf2f(u16 h) {
  return __uint_as_float((unsigned)h << 16);
}
__device__ __forceinline__ void gload16(const void* g, void* l) {
  typedef __attribute__((address_space(1))) unsigned int gu32;
  typedef __attribute__((address_space(3))) unsigned int lu32;
  __builtin_amdgcn_global_load_lds((const gu32*)g, (lu32*)l, 16, 0, 0);
}

// ---------------- fp32 -> bf16 hi/lo split ----------------
__global__ __launch_bounds__(256) void convert_split(
    const float* __restrict__ in, u16* __restrict__ hi, u16* __restrict__ lo, int n) {
  int i4 = (blockIdx.x * 256 + threadIdx.x) * 4;
  if (i4 >= n) return;
  float4 v = *(const float4*)(in + i4);
  u16 h0,l0,h1,l1,h2,l2,h3,l3;
  bsplit(v.x,h0,l0); bsplit(v.y,h1,l1); bsplit(v.z,h2,l2); bsplit(v.w,h3,l3);
  hi[i4]=h0; hi[i4+1]=h1; hi[i4+2]=h2; hi[i4+3]=h3;
  lo[i4]=l0; lo[i4+1]=l1; lo[i4+2]=l2; lo[i4+3]=l3;
}

// pad x_proj_w (48x512) to 128x512 and split
__global__ __launch_bounds__(256) void padxp_convert(
    const float* __restrict__ xpw, u16* __restrict__ hi, u16* __restrict__ lo) {
  int i4 = (blockIdx.x * 256 + threadIdx.x) * 4;   // over 128*512
  if (i4 >= 128 * 512) return;
  int row = i4 >> 9;
  float4 v = row < 48 ? *(const float4*)(xpw + i4) : make_float4(0.f,0.f,0.f,0.f);
  u16 h0,l0,h1,l1,h2,l2,h3,l3;
  bsplit(v.x,h0,l0); bsplit(v.y,h1,l1); bsplit(v.z,h2,l2); bsplit(v.w,h3,l3);
  hi[i4]=h0; hi[i4+1]=h1; hi[i4+2]=h2; hi[i4+3]=h3;
  lo[i4]=l0; lo[i4+1]=l1; lo[i4+2]=l2; lo[i4+3]=l3;
}

// ---------------- im2col: 8 contiguous pixels per thread ----------------
__global__ __launch_bounds__(256) void im2col_chunk(
    const float* __restrict__ x, const int* __restrict__ perm,
    u16* __restrict__ Ph, u16* __restrict__ Pl, int l0, int lg) {
  int idx = blockIdx.x * 256 + threadIdx.x;   // CR*24
  int k8 = idx % 24;
  int rb = idx / 24;
  int c = k8 >> 3, uu = k8 & 7;
  int b = rb >> lg;
  int l = l0 + (rb & ((1 << lg) - 1));
  int j = perm[l];
  int py = j >> 6, px = j & 63;
  const float* src = x + (((size_t)b * 3 + c) * 512 + (size_t)(py * 8 + uu)) * 512 + px * 8;
  float4 v0 = *(const float4*)src;
  float4 v1 = *(const float4*)(src + 4);
  ushort4 h0, l0v, h1, l1v; u16 a, bb;
  bsplit(v0.x,a,bb); h0.x=a; l0v.x=bb;
  bsplit(v0.y,a,bb); h0.y=a; l0v.y=bb;
  bsplit(v0.z,a,bb); h0.z=a; l0v.z=bb;
  bsplit(v0.w,a,bb); h0.w=a; l0v.w=bb;
  bsplit(v1.x,a,bb); h1.x=a; l1v.x=bb;
  bsplit(v1.y,a,bb); h1.y=a; l1v.y=bb;
  bsplit(v1.z,a,bb); h1.z=a; l1v.z=bb;
  bsplit(v1.w,a,bb); h1.w=a; l1v.w=bb;
  size_t o = (size_t)rb * 192 + c * 64 + uu * 8;
  *(ushort4*)(Ph + o) = h0; *(ushort4*)(Ph + o + 4) = h1;
  *(ushort4*)(Pl + o) = l0v; *(ushort4*)(Pl + o + 4) = l1v;
}

// ---------------- 128x128 MFMA GEMM, 3-term bf16 split, global_load_lds staging ----
template<bool BIAS, bool ACC>
__global__ __launch_bounds__(256) void gemm128_bf3(
    const u16* __restrict__ Ah, const u16* __restrict__ Al,
    const u16* __restrict__ Wh, const u16* __restrict__ Wl,
    const float* __restrict__ bias, float* __restrict__ C,
    int N, int K) {
  __shared__ u16 lds[16384];   // Ah | Al | Wh | Wl, each 128 rows x 32 u16
  const int bm = blockIdx.y * 128, bn = blockIdx.x * 128;
  const int t = threadIdx.x;
  const int lane = t & 63, w = t >> 6;
  const int wr = w >> 1, wc = w & 1;
  const int l15 = lane & 15, kg = lane >> 4;

  const int c0 = w * 2;
  const int srow = lane >> 2;
  const int scol = (lane & 3) * 8;
  const u16* gsrc[8];
  u16* ldst[8];
  {
    size_t ra0 = (size_t)(bm + c0 * 16 + srow) * K + scol;
    size_t ra1 = (size_t)(bm + c0 * 16 + 16 + srow) * K + scol;
    size_t rw0 = (size_t)(bn + c0 * 16 + srow) * K + scol;
    size_t rw1 = (size_t)(bn + c0 * 16 + 16 + srow) * K + scol;
    gsrc[0] = Ah + ra0; gsrc[1] = Ah + ra1;
    gsrc[2] = Al + ra0; gsrc[3] = Al + ra1;
    gsrc[4] = Wh + rw0; gsrc[5] = Wh + rw1;
    gsrc[6] = Wl + rw0; gsrc[7] = Wl + rw1;
    ldst[0] = lds + c0 * 512;          ldst[1] = lds + c0 * 512 + 512;
    ldst[2] = lds + 4096 + c0 * 512;   ldst[3] = lds + 4096 + c0 * 512 + 512;
    ldst[4] = lds + 8192 + c0 * 512;   ldst[5] = lds + 8192 + c0 * 512 + 512;
    ldst[6] = lds + 12288 + c0 * 512;  ldst[7] = lds + 12288 + c0 * 512 + 512;
  }
  const u16* pa_h = lds + (size_t)(wr * 64 + l15) * 32 + kg * 8;
  const u16* pa_l = pa_h + 4096;
  const u16* pb_h = lds + 8192 + (size_t)(wc * 64 + l15) * 32 + kg * 8;
  const u16* pb_l = pb_h + 4096;

  f32x4 acc[4][4] = {};
  for (int k0 = 0; k0 < K; k0 += 32) {
    __syncthreads();
    #pragma unroll
    for (int i = 0; i < 8; ++i) { gload16(gsrc[i], ldst[i]); gsrc[i] += 32; }
    __syncthreads();
    bf16x8 ah[4], al[4], bh[4], bl[4];
    #pragma unroll
    for (int i = 0; i < 4; ++i) {
      ah[i] = *(const bf16x8*)(pa_h + i * 512);
      al[i] = *(const bf16x8*)(pa_l + i * 512);
      bh[i] = *(const bf16x8*)(pb_h + i * 512);
      bl[i] = *(const bf16x8*)(pb_l + i * 512);
    }
    #pragma unroll
    for (int i = 0; i < 4; ++i)
      #pragma unroll
      for (int j = 0; j < 4; ++j) {
        acc[i][j] = __builtin_amdgcn_mfma_f32_16x16x32_bf16(ah[i], bh[j], acc[i][j], 0, 0, 0);
        acc[i][j] = __builtin_amdgcn_mfma_f32_16x16x32_bf16(ah[i], bl[j], acc[i][j], 0, 0, 0);
        acc[i][j] = __builtin_amdgcn_mfma_f32_16x16x32_bf16(al[i], bh[j], acc[i][j], 0, 0, 0);
      }
  }

  const int row0 = bm + wr * 64 + kg * 4;
  const int col0 = bn + wc * 64 + l15;
  #pragma unroll
  for (int i = 0; i < 4; ++i) {
    #pragma unroll
    for (int q = 0; q < 4; ++q) {
      int row = row0 + i * 16 + q;
      #pragma unroll
      for (int j = 0; j < 4; ++j) {
        int col = col0 + j * 16;
        size_t o = (size_t)row * N + col;
        float v = acc[i][j][q];
        if (BIAS) v += bias[col];
        if (ACC) v += C[o];
        C[o] = v;
      }
    }
  }
}

// ---------------- RMSNorm: one wave per row, float4 ----------------
__global__ __launch_bounds__(256) void rmsnorm_rows(
    const float* __restrict__ emb, const float* __restrict__ w,
    u16* __restrict__ uh, u16* __restrict__ ul, int l0, int lg) {
  int wv = threadIdx.x >> 6, lane = threadIdx.x & 63;
  int rb = blockIdx.x * 4 + wv;
  size_t grow = ((size_t)(rb >> lg) << 12) + l0 + (rb & ((1 << lg) - 1));
  float4 v = *(const float4*)&emb[grow * 256 + lane * 4];
  float sq = v.x*v.x + v.y*v.y + v.z*v.z + v.w*v.w;
  #pragma unroll
  for (int m = 1; m < 64; m <<= 1) sq += __shfl_xor(sq, m, 64);
  float r = rsqrtf(sq * (1.f / 256.f) + 1e-5f);
  float4 wt = *(const float4*)&w[lane * 4];
  ushort4 hh, ll; u16 a, b;
  bsplit(v.x * r * wt.x, a, b); hh.x = a; ll.x = b;
  bsplit(v.y * r * wt.y, a, b); hh.y = a; ll.y = b;
  bsplit(v.z * r * wt.z, a, b); hh.z = a; ll.z = b;
  bsplit(v.w * r * wt.w, a, b); hh.w = a; ll.w = b;
  *(ushort4*)&uh[(size_t)rb * 256 + lane * 4] = hh;
  *(ushort4*)&ul[(size_t)rb * 256 + lane * 4] = ll;
}

// ---------------- causal depthwise conv + silu, 4 chan x 8 rows per thread ------
__global__ __launch_bounds__(256) void conv_chunk(
    const float* __restrict__ xz, const float* __restrict__ cstate,
    const float* __restrict__ cw, const float* __restrict__ cb,
    u16* __restrict__ xch, u16* __restrict__ xcl, int l0, int lg) {
  int idx = blockIdx.x * 256 + threadIdx.x;   // (CR/8)*128
  int cg = idx & 127;
  int rg = idx >> 7;
  int d4 = cg * 4;
  int rb0 = rg * 8;
  int b = rb0 >> lg;
  int loff0 = rb0 & ((1 << lg) - 1);
  float4 w0 = *(const float4*)(cw + (d4+0)*4);
  float4 w1 = *(const float4*)(cw + (d4+1)*4);
  float4 w2 = *(const float4*)(cw + (d4+2)*4);
  float4 w3 = *(const float4*)(cw + (d4+3)*4);
  float4 bias = *(const float4*)(cb + d4);
  float4 xv[11];
  #pragma unroll
  for (int j = 0; j < 3; ++j) {
    if (loff0 == 0) {
      if (l0 == 0) xv[j] = make_float4(0.f,0.f,0.f,0.f);
      else xv[j] = *(const float4*)(cstate + ((size_t)b*3 + j)*512 + d4);
    } else {
      xv[j] = *(const float4*)(xz + ((size_t)(rb0 - 3 + j))*1024 + d4);
    }
  }
  #pragma unroll
  for (int i = 0; i < 8; ++i)
    xv[3+i] = *(const float4*)(xz + ((size_t)(rb0 + i))*1024 + d4);
  #pragma unroll
  for (int i = 0; i < 8; ++i) {
    float4 a = bias;
    #pragma unroll
    for (int k = 0; k < 4; ++k) {
      float4 xk = xv[i + k];
      a.x = fmaf(xk.x, ((const float*)&w0)[k], a.x);
      a.y = fmaf(xk.y, ((const float*)&w1)[k], a.y);
      a.z = fmaf(xk.z, ((const float*)&w2)[k], a.z);
      a.w = fmaf(xk.w, ((const float*)&w3)[k], a.w);
    }
    float4 val;
    val.x = a.x / (1.f + __expf(-a.x));
    val.y = a.y / (1.f + __expf(-a.y));
    val.z = a.z / (1.f + __expf(-a.z));
    val.w = a.w / (1.f + __expf(-a.w));
    ushort4 hh, ll; u16 p, q;
    bsplit(val.x,p,q); hh.x=p; ll.x=q;
    bsplit(val.y,p,q); hh.y=p; ll.y=q;
    bsplit(val.z,p,q); hh.z=p; ll.z=q;
    bsplit(val.w,p,q); hh.w=p; ll.w=q;
    size_t o = (size_t)(rb0 + i) * 512 + d4;
    *(ushort4*)(xch + o) = hh;
    *(ushort4*)(xcl + o) = ll;
  }
}

__global__ __launch_bounds__(256) void save_hist(
    const float* __restrict__ xz, float* __restrict__ cstate, int lg) {
  int idx = blockIdx.x * 256 + threadIdx.x;   // 8*3*512
  int d = idx & 511;
  int r = (idx >> 9) % 3;
  int b = (idx >> 9) / 3;
  int CL = 1 << lg;
  cstate[idx] = xz[((size_t)(b << lg) + CL - 3 + r) * 1024 + d];
}

// ---------------- dt = softplus(xdbl[:, :16] @ dt_w^T + dt_b), 4 chan/thread ----
__global__ __launch_bounds__(256) void dt_chunk(
    const float* __restrict__ xdbl, const float* __restrict__ dtw,
    const float* __restrict__ dtbias, float* __restrict__ dtv) {
  int idx = blockIdx.x * 256 + threadIdx.x;   // CR*128
  int cg = idx & 127;
  int row = idx >> 7;
  int d4 = cg * 4;
  const float* xd = xdbl + (size_t)row * 128;
  float xr[16];
  #pragma unroll
  for (int r = 0; r < 16; r += 4) {
    float4 v = *(const float4*)(xd + r);
    xr[r] = v.x; xr[r+1] = v.y; xr[r+2] = v.z; xr[r+3] = v.w;
  }
  float4 bias = *(const float4*)(dtbias + d4);
  float out[4];
  #pragma unroll
  for (int c = 0; c < 4; ++c) {
    const float* wr = dtw + (size_t)(d4 + c) * 16;
    float a = ((const float*)&bias)[c];
    #pragma unroll
    for (int r = 0; r < 16; ++r) a = fmaf(xr[r], wr[r], a);
    out[c] = (a > 20.f) ? a : log1pf(__expf(a));
  }
  *(float4*)(dtv + (size_t)row * 512 + d4) = make_float4(out[0], out[1], out[2], out[3]);
}

// ---------------- segmented scan pass 1 ----------------
__global__ __launch_bounds__(256) void seg_state(
    const float* __restrict__ dtv, const u16* __restrict__ xch, const u16* __restrict__ xcl,
    const float* __restrict__ xdbl, const float* __restrict__ A_log,
    float* __restrict__ h_end, float* __restrict__ sdt_out, int CL, int TL) {
  int d = blockIdx.x * 256 + threadIdx.x;
  int b = blockIdx.y, s = blockIdx.z;
  float4 A0 = *(const float4*)(A_log + d * 16);
  float4 A1 = *(const float4*)(A_log + d * 16 + 4);
  float4 A2 = *(const float4*)(A_log + d * 16 + 8);
  float4 A3 = *(const float4*)(A_log + d * 16 + 12);
  float An[16] = {-__expf(A0.x),-__expf(A0.y),-__expf(A0.z),-__expf(A0.w),
                  -__expf(A1.x),-__expf(A1.y),-__expf(A1.z),-__expf(A1.w),
                  -__expf(A2.x),-__expf(A2.y),-__expf(A2.z),-__expf(A2.w),
                  -__expf(A3.x),-__expf(A3.y),-__expf(A3.z),-__expf(A3.w)};
  float h[16];
  #pragma unroll
  for (int n = 0; n < 16; ++n) h[n] = 0.f;
  float sdt = 0.f;
  size_t row = (size_t)b * CL + (size_t)s * TL;
  for (int l = 0; l < TL; ++l, ++row) {
    float dt_ = dtv[row * 512 + d];
    float xv = bf2f(xch[row * 512 + d]) + bf2f(xcl[row * 512 + d]);
    const float* xr = xdbl + row * 128;
    float4 B0 = *(const float4*)(xr + 16);
    float4 B1 = *(const float4*)(xr + 20);
    float4 B2 = *(const float4*)(xr + 24);
    float4 B3 = *(const float4*)(xr + 28);
    float bb[16] = {B0.x,B0.y,B0.z,B0.w,B1.x,B1.y,B1.z,B1.w,
                    B2.x,B2.y,B2.z,B2.w,B3.x,B3.y,B3.z,B3.w};
    float t1 = dt_ * xv;
    #pragma unroll
    for (int n = 0; n < 16; ++n)
      h[n] = fmaf(h[n], __expf(dt_ * An[n]), t1 * bb[n]);
    sdt += dt_;
  }
  size_t o = (((size_t)s * 8 + b) * 512 + d) * 16;
  #pragma unroll
  for (int n = 0; n < 16; n += 4)
    *(float4*)(h_end + o + n) = make_float4(h[n], h[n+1], h[n+2], h[n+3]);
  sdt_out[((size_t)s * 8 + b) * 512 + d] = sdt;
}

// ---------------- pass 2: serial combine (in-place h_end -> h_in) ----------------
__global__ __launch_bounds__(256) void seg_combine(
    float* __restrict__ h_end, const float* __restrict__ sdt,
    const float* __restrict__ A_log, float* __restrict__ hstate, int S, int first) {
  int idx = blockIdx.x * 256 + threadIdx.x;  // 65536 = 8*512*16
  int n = idx & 15, d = (idx >> 4) & 511, b = idx >> 13;
  float An = -__expf(A_log[d * 16 + n]);
  size_t hidx = ((size_t)b * 512 + d) * 16 + n;
  float acc = first ? 0.f : hstate[hidx];
  for (int s = 0; s < S; ++s) {
    size_t o = (((size_t)s * 8 + b) * 512 + d) * 16 + n;
    float he = h_end[o];
    h_end[o] = acc;
    float P = __expf(An * sdt[((size_t)s * 8 + b) * 512 + d]);
    acc = fmaf(acc, P, he);
  }
  hstate[hidx] = acc;
}

// ---------------- pass 3: scan from h_in, fused C-reduce + z-gate + y write ------
__global__ __launch_bounds__(256) void seg_scan(
    const float* __restrict__ dtv, const u16* __restrict__ xch, const u16* __restrict__ xcl,
    const float* __restrict__ xdbl, const float* __restrict__ xz,
    const float* __restrict__ A_log, const float* __restrict__ D_skip,
    const float* __restrict__ h_in, u16* __restrict__ yh, u16* __restrict__ yl,
    int CL, int TL) {
  int d = blockIdx.x * 256 + threadIdx.x;
  int b = blockIdx.y, s = blockIdx.z;
  float4 A0 = *(const float4*)(A_log + d * 16);
  float4 A1 = *(const float4*)(A_log + d * 16 + 4);
  float4 A2 = *(const float4*)(A_log + d * 16 + 8);
  float4 A3 = *(const float4*)(A_log + d * 16 + 12);
  float An[16] = {-__expf(A0.x),-__expf(A0.y),-__expf(A0.z),-__expf(A0.w),
                  -__expf(A1.x),-__expf(A1.y),-__expf(A1.z),-__expf(A1.w),
                  -__expf(A2.x),-__expf(A2.y),-__expf(A2.z),-__expf(A2.w),
                  -__expf(A3.x),-__expf(A3.y),-__expf(A3.z),-__expf(A3.w)};
  float Dd = D_skip[d];
  size_t o = (((size_t)s * 8 + b) * 512 + d) * 16;
  float h[16];
  #pragma unroll
  for (int n = 0; n < 16; n += 4) {
    float4 hv = *(const float4*)(h_in + o + n);
    h[n] = hv.x; h[n+1] = hv.y; h[n+2] = hv.z; h[n+3] = hv.w;
  }
  size_t row = (size_t)b * CL + (size_t)s * TL;
  for (int l = 0; l < TL; ++l, ++row) {
    float dt_ = dtv[row * 512 + d];
    float xv = bf2f(xch[row * 512 + d]) + bf2f(xcl[row * 512 + d]);
    const float* xr = xdbl + row * 128;
    float4 B0 = *(const float4*)(xr + 16);
    float4 B1 = *(const float4*)(xr + 20);
    float4 B2 = *(const float4*)(xr + 24);
    float4 B3 = *(const float4*)(xr + 28);
    float4 C0 = *(const float4*)(xr + 32);
    float4 C1 = *(const float4*)(xr + 36);
    float4 C2 = *(const float4*)(xr + 40);
    float4 C3 = *(const float4*)(xr + 44);
    float bb[16] = {B0.x,B0.y,B0.z,B0.w,B1.x,B1.y,B1.z,B1.w,
                    B2.x,B2.y,B2.z,B2.w,B3.x,B3.y,B3.z,B3.w};
    float cc[16] = {C0.x,C0.y,C0.z,C0.w,C1.x,C1.y,C1.z,C1.w,
                    C2.x,C2.y,C2.z,C2.w,C3.x,C3.y,C3.z,C3.w};
    float t1 = dt_ * xv;
    float acc = 0.f;
    #pragma unroll
    for (int n = 0; n < 16; ++n) {
      h[n] = fmaf(h[n], __expf(dt_ * An[n]), t1 * bb[n]);
      acc = fmaf(h[n], cc[n], acc);
    }
    float zv = xz[row * 1024 + 512 + d];
    float sig = 1.f / (1.f + __expf(-zv));
    float val = fmaf(xv, Dd, acc) * (zv * sig);
    u16 hh, ll; bsplit(val, hh, ll);
    yh[row * 512 + d] = hh;
    yl[row * 512 + d] = ll;
  }
}

// ---------------- scatter chunk rows into global emb (fallback) ----------------
template<bool ADD>
__global__ __launch_bounds__(256) void scatter_rows(
    const float* __restrict__ E, float* __restrict__ emb, int l0, int lg) {
  int wv = threadIdx.x >> 6, lane = threadIdx.x & 63;
  int rb = blockIdx.x * 4 + wv;
  size_t grow = ((size_t)(rb >> lg) << 12) + l0 + (rb & ((1 << lg) - 1));
  float4 v = *(const float4*)&E[(size_t)rb * 256 + lane * 4];
  float* dst = &emb[grow * 256 + lane * 4];
  if (ADD) {
    float4 o = *(const float4*)dst;
    v.x += o.x; v.y += o.y; v.z += o.z; v.w += o.w;
  }
  *(float4*)dst = v;
}

// ---------------- final rmsnorm + pooling: wave-per-row, no barriers ----------------
__global__ __launch_bounds__(256) void normpool_partial(
    const float* __restrict__ emb, const float* __restrict__ nf,
    float* __restrict__ part) {
  int b = blockIdx.x, cb = blockIdx.y;           // cb 0..63
  int wv = threadIdx.x >> 6, lane = threadIdx.x & 63;
  int p = cb * 4 + wv;                            // 0..255
  float4 acc = make_float4(0.f,0.f,0.f,0.f);
  #pragma unroll 4
  for (int i = 0; i < 16; ++i) {
    size_t row = (size_t)b * 4096 + p * 16 + i;
    float4 v = *(const float4*)&emb[row * 256 + lane * 4];
    float sq = v.x*v.x + v.y*v.y + v.z*v.z + v.w*v.w;
    #pragma unroll
    for (int m = 1; m < 64; m <<= 1) sq += __shfl_xor(sq, m, 64);
    float r = rsqrtf(sq * (1.f / 256.f) + 1e-5f);
    acc.x = fmaf(v.x, r, acc.x);
    acc.y = fmaf(v.y, r, acc.y);
    acc.z = fmaf(v.z, r, acc.z);
    acc.w = fmaf(v.w, r, acc.w);
  }
  float4 w = *(const float4*)&nf[lane * 4];
  acc.x *= w.x; acc.y *= w.y; acc.z *= w.z; acc.w *= w.w;
  *(float4*)&part[((size_t)b * 256 + p) * 256 + lane * 4] = acc;
}

__global__ __launch_bounds__(256) void pool_reduce_kernel(
    const float* __restrict__ part, float* __restrict__ pooled) {
  int b = blockIdx.x, t = threadIdx.x;
  float s = 0.f;
  for (int c = 0; c < 256; ++c) s += part[((size_t)b * 256 + c) * 256 + t];
  pooled[b * 256 + t] = s * (1.f / 4096.f);
}

__global__ __launch_bounds__(128) void head_kernel(
    const float* __restrict__ pooled, const float* __restrict__ hw,
    const float* __restrict__ hb, float* __restrict__ out) {
  int t = threadIdx.x;
  if (t < 80) {
    int b = t / 10, c = t % 10;
    float a = hb[c];
    for (int dd = 0; dd < 256; ++dd) a = fmaf(pooled[b * 256 + dd], hw[c * 256 + dd], a);
    out[t] = a;
  }
}

extern "C" void kernel_launch(void* const* d_in, const int* in_sizes, int n_in,
                              void* d_out, int out_size, void* d_ws, size_t ws_size,
                              hipStream_t stream) {
  const float* x         = (const float*)d_in[0];
  const int*   perm      = (const int*)d_in[1];
  const float* patch_w   = (const float*)d_in[2];
  const float* patch_b   = (const float*)d_in[3];
  const float* norm_w    = (const float*)d_in[4];
  const float* in_proj_w = (const float*)d_in[5];
  const float* conv_w    = (const float*)d_in[6];
  const float* conv_b    = (const float*)d_in[7];
  const float* x_proj_w  = (const float*)d_in[8];
  const float* dt_w      = (const float*)d_in[9];
  const float* dt_b      = (const float*)d_in[10];
  const float* A_log     = (const float*)d_in[11];
  const float* D_skip    = (const float*)d_in[12];
  const float* out_w     = (const float*)d_in[13];
  const float* norm_f    = (const float*)d_in[14];
  const float* head_w    = (const float*)d_in[15];
  const float* head_b    = (const float*)d_in[16];
  float* outp = (float*)d_out;

  const size_t M = (size_t)BATCH * SEQL;  // 32768
  float* ws     = (float*)d_ws;
  float* emb    = ws;                       // M*256
  float* hstate = emb + M * 256;            // 65536
  float* cstate = hstate + 65536;           // 12288
  float* part   = cstate + 12288;           // 8*256*256
  float* pooled = part + 8 * 256 * 256;     // 2048
  float* h_end  = pooled + 2048;            // 64*65536
  float* sdtb   = h_end + 64 * 65536;       // 64*4096
  u16* wi_h = (u16*)(sdtb + 64 * 4096);     // 1024*256
  u16* wi_l = wi_h + 262144;
  u16* wo_h = wi_l + 262144;                // 256*512
  u16* wo_l = wo_h + 131072;
  u16* wx_h = wo_l + 131072;                // 128*512
  u16* wx_l = wx_h + 65536;
  u16* wp_h = wx_l + 65536;                 // 256*192
  u16* wp_l = wp_h + 49152;
  float* cbase = (float*)(wp_l + 49152);

  size_t fixedF = (size_t)(cbase - ws);
  int CL = 4096;
  while (CL > 64) {
    size_t need = (fixedF + (size_t)8 * CL * 2944) * sizeof(float);
    if (need <= ws_size) break;
    CL >>= 1;
  }
  int lg = 31 - __builtin_clz((unsigned)CL);
  int nch = 4096 / CL;
  int CR = 8 * CL;
  int S = CL / 64, TL = 64;
  bool ident = (nch == 1);

  u16*   u_h  = (u16*)cbase;                        // CR*256
  u16*   u_l  = u_h + (size_t)CR * 256;
  float* xz   = (float*)(u_l + (size_t)CR * 256);   // CR*1024
  u16*   xc_h = (u16*)(xz + (size_t)CR * 1024);     // CR*512
  u16*   xc_l = xc_h + (size_t)CR * 512;
  float* xdbl = (float*)(xc_l + (size_t)CR * 512);  // CR*128
  float* dtvb = xdbl + (size_t)CR * 128;            // CR*512
  u16*   y_h  = (u16*)(dtvb + (size_t)CR * 512);    // CR*512
  u16*   y_l  = y_h + (size_t)CR * 512;
  u16*   P_h  = (u16*)xz;                           // CR*192 (alias)
  u16*   P_l  = P_h + (size_t)CR * 192;
  float* E    = xz + (size_t)CR * 512;              // CR*256 (alias)

  // ---- patch embed ----
  convert_split<<<48, 256, 0, stream>>>(patch_w, wp_h, wp_l, 49152);
  for (int c = 0; c < nch; ++c) {
    int l0 = c * CL;
    im2col_chunk<<<CR * 24 / 256, 256, 0, stream>>>(x, perm, P_h, P_l, l0, lg);
    if (ident) {
      gemm128_bf3<true, false><<<dim3(2, CR / 128), 256, 0, stream>>>(
          P_h, P_l, wp_h, wp_l, patch_b, emb, 256, 192);
    } else {
      gemm128_bf3<true, false><<<dim3(2, CR / 128), 256, 0, stream>>>(
          P_h, P_l, wp_h, wp_l, patch_b, E, 256, 192);
      scatter_rows<false><<<CR / 4, 256, 0, stream>>>(E, emb, l0, lg);
    }
  }

  // ---- layers ----
  for (int layer = 0; layer < 4; ++layer) {
    convert_split<<<256, 256, 0, stream>>>(in_proj_w + (size_t)layer * 262144, wi_h, wi_l, 262144);
    convert_split<<<128, 256, 0, stream>>>(out_w + (size_t)layer * 131072, wo_h, wo_l, 131072);
    padxp_convert<<<64, 256, 0, stream>>>(x_proj_w + (size_t)layer * 48 * 512, wx_h, wx_l);
    const float* Alog_l = A_log + layer * 8192;
    for (int c = 0; c < nch; ++c) {
      int l0 = c * CL;
      rmsnorm_rows<<<CR / 4, 256, 0, stream>>>(emb, norm_w + layer * 256, u_h, u_l, l0, lg);
      gemm128_bf3<false, false><<<dim3(8, CR / 128), 256, 0, stream>>>(
          u_h, u_l, wi_h, wi_l, nullptr, xz, 1024, 256);
      conv_chunk<<<CR / 16, 256, 0, stream>>>(
          xz, cstate, conv_w + layer * 2048, conv_b + layer * 512, xc_h, xc_l, l0, lg);
      if (!ident) save_hist<<<48, 256, 0, stream>>>(xz, cstate, lg);
      gemm128_bf3<false, false><<<dim3(1, CR / 128), 256, 0, stream>>>(
          xc_h, xc_l, wx_h, wx_l, nullptr, xdbl, 128, 512);
      dt_chunk<<<CR / 2, 256, 0, stream>>>(
          xdbl, dt_w + layer * 8192, dt_b + layer * 512, dtvb);
      seg_state<<<dim3(2, 8, S), 256, 0, stream>>>(
          dtvb, xc_h, xc_l, xdbl, Alog_l, h_end, sdtb, CL, TL);
      seg_combine<<<256, 256, 0, stream>>>(
          h_end, sdtb, Alog_l, hstate, S, c == 0 ? 1 : 0);
      seg_scan<<<dim3(2, 8, S), 256, 0, stream>>>(
          dtvb, xc_h, xc_l, xdbl, xz, Alog_l, D_skip + layer * 512, h_end,
          y_h, y_l, CL, TL);
      if (ident) {
        gemm128_bf3<false, true><<<dim3(2, CR / 128), 256, 0, stream>>>(
            y_h, y_l, wo_h, wo_l, nullptr, emb, 256, 512);
      } else {
        gemm128_bf3<false, false><<<dim3(2, CR / 128), 256, 0, stream>>>(
            y_h, y_l, wo_h, wo_l, nullptr, E, 256, 512);
        scatter_rows<true><<<CR / 4, 256, 0, stream>>>(E, emb, l0, lg);
      }
    }
  }

  // ---- final norm + pool + head ----
  normpool_partial<<<dim3(8, 64), 256, 0, stream>>>(emb, norm_f, part);
  pool_reduce_kernel<<<8, 256, 0, stream>>>(part, pooled);
  head_kernel<<<1, 128, 0, stream>>>(pooled, head_w, head_b, outp);
}

// Round 7
// 2105.454 us; speedup vs baseline: 7.0479x; 1.1326x over previous
//
#include <hip/hip_runtime.h>
#include <hip/hip_bf16.h>
#include <math.h>

#define BATCH 8
#define SEQL  4096

typedef unsigned short u16;
typedef short bf16x8 __attribute__((ext_vector_type(8)));
typedef float f32x4 __attribute__((ext_vector_type(4)));

__device__ __forceinline__ u16 bfr(float a) {
  unsigned u = __float_as_uint(a);
  return (u16)((u + 0x7FFFu + ((u >> 16) & 1u)) >> 16);
}
__device__ __forceinline__ void bsplit(float a, u16& h, u16& l) {
  u16 hb = bfr(a);
  float hf = __uint_as_float((unsigned)hb << 16);
  h = hb;
  l = bfr(a - hf);
}
__device__ __forceinline__ float bf2f(u16 h) {
  return __uint_as_float((unsigned)h << 16);
}
__device__ __forceinline__ void gload16(const void* g, void* l) {
  typedef __attribute__((address_space(1))) unsigned int gu32;
  typedef __attribute__((address_space(3))) unsigned int lu32;
  __builtin_amdgcn_global_load_lds((const gu32*)g, (lu32*)l, 16, 0, 0);
}

// ---------------- fp32 -> bf16 hi/lo split ----------------
__global__ __launch_bounds__(256) void convert_split(
    const float* __restrict__ in, u16* __restrict__ hi, u16* __restrict__ lo, int n) {
  int i4 = (blockIdx.x * 256 + threadIdx.x) * 4;
  if (i4 >= n) return;
  float4 v = *(const float4*)(in + i4);
  u16 h0,l0,h1,l1,h2,l2,h3,l3;
  bsplit(v.x,h0,l0); bsplit(v.y,h1,l1); bsplit(v.z,h2,l2); bsplit(v.w,h3,l3);
  hi[i4]=h0; hi[i4+1]=h1; hi[i4+2]=h2; hi[i4+3]=h3;
  lo[i4]=l0; lo[i4+1]=l1; lo[i4+2]=l2; lo[i4+3]=l3;
}

// pad x_proj_w (48x512) to 128x512 and split
__global__ __launch_bounds__(256) void padxp_convert(
    const float* __restrict__ xpw, u16* __restrict__ hi, u16* __restrict__ lo) {
  int i4 = (blockIdx.x * 256 + threadIdx.x) * 4;   // over 128*512
  if (i4 >= 128 * 512) return;
  int row = i4 >> 9;
  float4 v = row < 48 ? *(const float4*)(xpw + i4) : make_float4(0.f,0.f,0.f,0.f);
  u16 h0,l0,h1,l1,h2,l2,h3,l3;
  bsplit(v.x,h0,l0); bsplit(v.y,h1,l1); bsplit(v.z,h2,l2); bsplit(v.w,h3,l3);
  hi[i4]=h0; hi[i4+1]=h1; hi[i4+2]=h2; hi[i4+3]=h3;
  lo[i4]=l0; lo[i4+1]=l1; lo[i4+2]=l2; lo[i4+3]=l3;
}

// ---------------- im2col: 8 contiguous pixels per thread ----------------
__global__ __launch_bounds__(256) void im2col_chunk(
    const float* __restrict__ x, const int* __restrict__ perm,
    u16* __restrict__ Ph, u16* __restrict__ Pl, int l0, int lg) {
  int idx = blockIdx.x * 256 + threadIdx.x;   // CR*24
  int k8 = idx % 24;
  int rb = idx / 24;
  int c = k8 >> 3, uu = k8 & 7;
  int b = rb >> lg;
  int l = l0 + (rb & ((1 << lg) - 1));
  int j = perm[l];
  int py = j >> 6, px = j & 63;
  const float* src = x + (((size_t)b * 3 + c) * 512 + (size_t)(py * 8 + uu)) * 512 + px * 8;
  float4 v0 = *(const float4*)src;
  float4 v1 = *(const float4*)(src + 4);
  ushort4 h0, l0v, h1, l1v; u16 a, bb;
  bsplit(v0.x,a,bb); h0.x=a; l0v.x=bb;
  bsplit(v0.y,a,bb); h0.y=a; l0v.y=bb;
  bsplit(v0.z,a,bb); h0.z=a; l0v.z=bb;
  bsplit(v0.w,a,bb); h0.w=a; l0v.w=bb;
  bsplit(v1.x,a,bb); h1.x=a; l1v.x=bb;
  bsplit(v1.y,a,bb); h1.y=a; l1v.y=bb;
  bsplit(v1.z,a,bb); h1.z=a; l1v.z=bb;
  bsplit(v1.w,a,bb); h1.w=a; l1v.w=bb;
  size_t o = (size_t)rb * 192 + c * 64 + uu * 8;
  *(ushort4*)(Ph + o) = h0; *(ushort4*)(Ph + o + 4) = h1;
  *(ushort4*)(Pl + o) = l0v; *(ushort4*)(Pl + o + 4) = l1v;
}

// ---------------- 128x128 MFMA GEMM, 3-term bf16 split, global_load_lds staging ----
// SPLIT: logical N=1024, cols<512 -> C (stride 512), cols>=512 -> C1 (stride 512)
template<bool BIAS, bool ACC, bool SPLIT>
__global__ __launch_bounds__(256) void gemm128_bf3(
    const u16* __restrict__ Ah, const u16* __restrict__ Al,
    const u16* __restrict__ Wh, const u16* __restrict__ Wl,
    const float* __restrict__ bias, float* __restrict__ C, float* __restrict__ C1,
    int N, int K) {
  __shared__ u16 lds[16384];   // Ah | Al | Wh | Wl, each 128 rows x 32 u16
  const int bm = blockIdx.y * 128, bn = blockIdx.x * 128;
  const int t = threadIdx.x;
  const int lane = t & 63, w = t >> 6;
  const int wr = w >> 1, wc = w & 1;
  const int l15 = lane & 15, kg = lane >> 4;

  const int c0 = w * 2;
  const int srow = lane >> 2;
  const int scol = (lane & 3) * 8;
  const u16* gsrc[8];
  u16* ldst[8];
  {
    size_t ra0 = (size_t)(bm + c0 * 16 + srow) * K + scol;
    size_t ra1 = (size_t)(bm + c0 * 16 + 16 + srow) * K + scol;
    size_t rw0 = (size_t)(bn + c0 * 16 + srow) * K + scol;
    size_t rw1 = (size_t)(bn + c0 * 16 + 16 + srow) * K + scol;
    gsrc[0] = Ah + ra0; gsrc[1] = Ah + ra1;
    gsrc[2] = Al + ra0; gsrc[3] = Al + ra1;
    gsrc[4] = Wh + rw0; gsrc[5] = Wh + rw1;
    gsrc[6] = Wl + rw0; gsrc[7] = Wl + rw1;
    ldst[0] = lds + c0 * 512;          ldst[1] = lds + c0 * 512 + 512;
    ldst[2] = lds + 4096 + c0 * 512;   ldst[3] = lds + 4096 + c0 * 512 + 512;
    ldst[4] = lds + 8192 + c0 * 512;   ldst[5] = lds + 8192 + c0 * 512 + 512;
    ldst[6] = lds + 12288 + c0 * 512;  ldst[7] = lds + 12288 + c0 * 512 + 512;
  }
  const u16* pa_h = lds + (size_t)(wr * 64 + l15) * 32 + kg * 8;
  const u16* pa_l = pa_h + 4096;
  const u16* pb_h = lds + 8192 + (size_t)(wc * 64 + l15) * 32 + kg * 8;
  const u16* pb_l = pb_h + 4096;

  f32x4 acc[4][4] = {};
  for (int k0 = 0; k0 < K; k0 += 32) {
    __syncthreads();
    #pragma unroll
    for (int i = 0; i < 8; ++i) { gload16(gsrc[i], ldst[i]); gsrc[i] += 32; }
    __syncthreads();
    bf16x8 ah[4], al[4], bh[4], bl[4];
    #pragma unroll
    for (int i = 0; i < 4; ++i) {
      ah[i] = *(const bf16x8*)(pa_h + i * 512);
      al[i] = *(const bf16x8*)(pa_l + i * 512);
      bh[i] = *(const bf16x8*)(pb_h + i * 512);
      bl[i] = *(const bf16x8*)(pb_l + i * 512);
    }
    #pragma unroll
    for (int i = 0; i < 4; ++i)
      #pragma unroll
      for (int j = 0; j < 4; ++j) {
        acc[i][j] = __builtin_amdgcn_mfma_f32_16x16x32_bf16(ah[i], bh[j], acc[i][j], 0, 0, 0);
        acc[i][j] = __builtin_amdgcn_mfma_f32_16x16x32_bf16(ah[i], bl[j], acc[i][j], 0, 0, 0);
        acc[i][j] = __builtin_amdgcn_mfma_f32_16x16x32_bf16(al[i], bh[j], acc[i][j], 0, 0, 0);
      }
  }

  const int row0 = bm + wr * 64 + kg * 4;
  const int col0 = bn + wc * 64 + l15;
  #pragma unroll
  for (int i = 0; i < 4; ++i) {
    #pragma unroll
    for (int q = 0; q < 4; ++q) {
      int row = row0 + i * 16 + q;
      #pragma unroll
      for (int j = 0; j < 4; ++j) {
        int col = col0 + j * 16;
        float v = acc[i][j][q];
        if (BIAS) v += bias[col];
        if (SPLIT) {
          float* dst = (col < 512) ? C : C1;
          dst[(size_t)row * 512 + (col & 511)] = v;
        } else {
          size_t o = (size_t)row * N + col;
          if (ACC) v += C[o];
          C[o] = v;
        }
      }
    }
  }
}

// ---------------- RMSNorm: one wave per row, float4 ----------------
__global__ __launch_bounds__(256) void rmsnorm_rows(
    const float* __restrict__ emb, const float* __restrict__ w,
    u16* __restrict__ uh, u16* __restrict__ ul, int l0, int lg) {
  int wv = threadIdx.x >> 6, lane = threadIdx.x & 63;
  int rb = blockIdx.x * 4 + wv;
  size_t grow = ((size_t)(rb >> lg) << 12) + l0 + (rb & ((1 << lg) - 1));
  float4 v = *(const float4*)&emb[grow * 256 + lane * 4];
  float sq = v.x*v.x + v.y*v.y + v.z*v.z + v.w*v.w;
  #pragma unroll
  for (int m = 1; m < 64; m <<= 1) sq += __shfl_xor(sq, m, 64);
  float r = rsqrtf(sq * (1.f / 256.f) + 1e-5f);
  float4 wt = *(const float4*)&w[lane * 4];
  ushort4 hh, ll; u16 a, b;
  bsplit(v.x * r * wt.x, a, b); hh.x = a; ll.x = b;
  bsplit(v.y * r * wt.y, a, b); hh.y = a; ll.y = b;
  bsplit(v.z * r * wt.z, a, b); hh.z = a; ll.z = b;
  bsplit(v.w * r * wt.w, a, b); hh.w = a; ll.w = b;
  *(ushort4*)&uh[(size_t)rb * 256 + lane * 4] = hh;
  *(ushort4*)&ul[(size_t)rb * 256 + lane * 4] = ll;
}

// ---------------- causal depthwise conv + silu, 4 chan x 8 rows per thread ------
// reads dense X buffer (CR x 512)
__global__ __launch_bounds__(256) void conv_chunk(
    const float* __restrict__ X, const float* __restrict__ cstate,
    const float* __restrict__ cw, const float* __restrict__ cb,
    u16* __restrict__ xch, u16* __restrict__ xcl, int l0, int lg) {
  int idx = blockIdx.x * 256 + threadIdx.x;   // (CR/8)*128
  int cg = idx & 127;
  int rg = idx >> 7;
  int d4 = cg * 4;
  int rb0 = rg * 8;
  int b = rb0 >> lg;
  int loff0 = rb0 & ((1 << lg) - 1);
  float4 w0 = *(const float4*)(cw + (d4+0)*4);
  float4 w1 = *(const float4*)(cw + (d4+1)*4);
  float4 w2 = *(const float4*)(cw + (d4+2)*4);
  float4 w3 = *(const float4*)(cw + (d4+3)*4);
  float4 bias = *(const float4*)(cb + d4);
  float4 xv[11];
  #pragma unroll
  for (int j = 0; j < 3; ++j) {
    if (loff0 == 0) {
      if (l0 == 0) xv[j] = make_float4(0.f,0.f,0.f,0.f);
      else xv[j] = *(const float4*)(cstate + ((size_t)b*3 + j)*512 + d4);
    } else {
      xv[j] = *(const float4*)(X + ((size_t)(rb0 - 3 + j))*512 + d4);
    }
  }
  #pragma unroll
  for (int i = 0; i < 8; ++i)
    xv[3+i] = *(const float4*)(X + ((size_t)(rb0 + i))*512 + d4);
  #pragma unroll
  for (int i = 0; i < 8; ++i) {
    float4 a = bias;
    #pragma unroll
    for (int k = 0; k < 4; ++k) {
      float4 xk = xv[i + k];
      a.x = fmaf(xk.x, ((const float*)&w0)[k], a.x);
      a.y = fmaf(xk.y, ((const float*)&w1)[k], a.y);
      a.z = fmaf(xk.z, ((const float*)&w2)[k], a.z);
      a.w = fmaf(xk.w, ((const float*)&w3)[k], a.w);
    }
    float4 val;
    val.x = a.x / (1.f + __expf(-a.x));
    val.y = a.y / (1.f + __expf(-a.y));
    val.z = a.z / (1.f + __expf(-a.z));
    val.w = a.w / (1.f + __expf(-a.w));
    ushort4 hh, ll; u16 p, q;
    bsplit(val.x,p,q); hh.x=p; ll.x=q;
    bsplit(val.y,p,q); hh.y=p; ll.y=q;
    bsplit(val.z,p,q); hh.z=p; ll.z=q;
    bsplit(val.w,p,q); hh.w=p; ll.w=q;
    size_t o = (size_t)(rb0 + i) * 512 + d4;
    *(ushort4*)(xch + o) = hh;
    *(ushort4*)(xcl + o) = ll;
  }
}

__global__ __launch_bounds__(256) void save_hist(
    const float* __restrict__ X, float* __restrict__ cstate, int lg) {
  int idx = blockIdx.x * 256 + threadIdx.x;   // 8*3*512
  int d = idx & 511;
  int r = (idx >> 9) % 3;
  int b = (idx >> 9) / 3;
  int CL = 1 << lg;
  cstate[idx] = X[((size_t)(b << lg) + CL - 3 + r) * 512 + d];
}

// ---------------- segmented scan pass 1 + fused dt GEMV/softplus ----------------
__global__ __launch_bounds__(256) void seg_state(
    const u16* __restrict__ xch, const u16* __restrict__ xcl,
    const float* __restrict__ xdbl, const float* __restrict__ A_log,
    const float* __restrict__ dtw, const float* __restrict__ dtb,
    float* __restrict__ dtv, float* __restrict__ h_end, float* __restrict__ sdt_out,
    int CL, int TL) {
  int d = blockIdx.x * 256 + threadIdx.x;
  int b = blockIdx.y, s = blockIdx.z;
  float4 A0 = *(const float4*)(A_log + d * 16);
  float4 A1 = *(const float4*)(A_log + d * 16 + 4);
  float4 A2 = *(const float4*)(A_log + d * 16 + 8);
  float4 A3 = *(const float4*)(A_log + d * 16 + 12);
  float An[16] = {-__expf(A0.x),-__expf(A0.y),-__expf(A0.z),-__expf(A0.w),
                  -__expf(A1.x),-__expf(A1.y),-__expf(A1.z),-__expf(A1.w),
                  -__expf(A2.x),-__expf(A2.y),-__expf(A2.z),-__expf(A2.w),
                  -__expf(A3.x),-__expf(A3.y),-__expf(A3.z),-__expf(A3.w)};
  float dw[16];
  #pragma unroll
  for (int r = 0; r < 16; r += 4) {
    float4 v = *(const float4*)(dtw + (size_t)d * 16 + r);
    dw[r] = v.x; dw[r+1] = v.y; dw[r+2] = v.z; dw[r+3] = v.w;
  }
  float dtb_r = dtb[d];
  float h[16];
  #pragma unroll
  for (int n = 0; n < 16; ++n) h[n] = 0.f;
  float sdt = 0.f;
  size_t row = (size_t)b * CL + (size_t)s * TL;
  for (int l = 0; l < TL; ++l, ++row) {
    const float* xr = xdbl + row * 128;
    float4 T0 = *(const float4*)(xr);
    float4 T1 = *(const float4*)(xr + 4);
    float4 T2 = *(const float4*)(xr + 8);
    float4 T3 = *(const float4*)(xr + 12);
    float tt[16] = {T0.x,T0.y,T0.z,T0.w,T1.x,T1.y,T1.z,T1.w,
                    T2.x,T2.y,T2.z,T2.w,T3.x,T3.y,T3.z,T3.w};
    float draw = dtb_r;
    #pragma unroll
    for (int r = 0; r < 16; ++r) draw = fmaf(tt[r], dw[r], draw);
    float dt_ = (draw > 20.f) ? draw : log1pf(__expf(draw));
    dtv[row * 512 + d] = dt_;
    float xv = bf2f(xch[row * 512 + d]) + bf2f(xcl[row * 512 + d]);
    float4 B0 = *(const float4*)(xr + 16);
    float4 B1 = *(const float4*)(xr + 20);
    float4 B2 = *(const float4*)(xr + 24);
    float4 B3 = *(const float4*)(xr + 28);
    float bb[16] = {B0.x,B0.y,B0.z,B0.w,B1.x,B1.y,B1.z,B1.w,
                    B2.x,B2.y,B2.z,B2.w,B3.x,B3.y,B3.z,B3.w};
    float t1 = dt_ * xv;
    #pragma unroll
    for (int n = 0; n < 16; ++n)
      h[n] = fmaf(h[n], __expf(dt_ * An[n]), t1 * bb[n]);
    sdt += dt_;
  }
  size_t o = (((size_t)s * 8 + b) * 512 + d) * 16;
  #pragma unroll
  for (int n = 0; n < 16; n += 4)
    *(float4*)(h_end + o + n) = make_float4(h[n], h[n+1], h[n+2], h[n+3]);
  sdt_out[((size_t)s * 8 + b) * 512 + d] = sdt;
}

// ---------------- pass 2: serial combine (in-place h_end -> h_in) ----------------
__global__ __launch_bounds__(256) void seg_combine(
    float* __restrict__ h_end, const float* __restrict__ sdt,
    const float* __restrict__ A_log, float* __restrict__ hstate, int S, int first) {
  int idx = blockIdx.x * 256 + threadIdx.x;  // 65536 = 8*512*16
  int n = idx & 15, d = (idx >> 4) & 511, b = idx >> 13;
  float An = -__expf(A_log[d * 16 + n]);
  size_t hidx = ((size_t)b * 512 + d) * 16 + n;
  float acc = first ? 0.f : hstate[hidx];
  for (int s = 0; s < S; ++s) {
    size_t o = (((size_t)s * 8 + b) * 512 + d) * 16 + n;
    float he = h_end[o];
    h_end[o] = acc;
    float P = __expf(An * sdt[((size_t)s * 8 + b) * 512 + d]);
    acc = fmaf(acc, P, he);
  }
  hstate[hidx] = acc;
}

// ---------------- pass 3: scan from h_in, fused C-reduce + z-gate + y write ------
__global__ __launch_bounds__(256) void seg_scan(
    const float* __restrict__ dtv, const u16* __restrict__ xch, const u16* __restrict__ xcl,
    const float* __restrict__ xdbl, const float* __restrict__ Z,
    const float* __restrict__ A_log, const float* __restrict__ D_skip,
    const float* __restrict__ h_in, u16* __restrict__ yh, u16* __restrict__ yl,
    int CL, int TL) {
  int d = blockIdx.x * 256 + threadIdx.x;
  int b = blockIdx.y, s = blockIdx.z;
  float4 A0 = *(const float4*)(A_log + d * 16);
  float4 A1 = *(const float4*)(A_log + d * 16 + 4);
  float4 A2 = *(const float4*)(A_log + d * 16 + 8);
  float4 A3 = *(const float4*)(A_log + d * 16 + 12);
  float An[16] = {-__expf(A0.x),-__expf(A0.y),-__expf(A0.z),-__expf(A0.w),
                  -__expf(A1.x),-__expf(A1.y),-__expf(A1.z),-__expf(A1.w),
                  -__expf(A2.x),-__expf(A2.y),-__expf(A2.z),-__expf(A2.w),
                  -__expf(A3.x),-__expf(A3.y),-__expf(A3.z),-__expf(A3.w)};
  float Dd = D_skip[d];
  size_t o = (((size_t)s * 8 + b) * 512 + d) * 16;
  float h[16];
  #pragma unroll
  for (int n = 0; n < 16; n += 4) {
    float4 hv = *(const float4*)(h_in + o + n);
    h[n] = hv.x; h[n+1] = hv.y; h[n+2] = hv.z; h[n+3] = hv.w;
  }
  size_t row = (size_t)b * CL + (size_t)s * TL;
  for (int l = 0; l < TL; ++l, ++row) {
    float dt_ = dtv[row * 512 + d];
    float xv = bf2f(xch[row * 512 + d]) + bf2f(xcl[row * 512 + d]);
    const float* xr = xdbl + row * 128;
    float4 B0 = *(const float4*)(xr + 16);
    float4 B1 = *(const float4*)(xr + 20);
    float4 B2 = *(const float4*)(xr + 24);
    float4 B3 = *(const float4*)(xr + 28);
    float4 C0 = *(const float4*)(xr + 32);
    float4 C1 = *(const float4*)(xr + 36);
    float4 C2 = *(const float4*)(xr + 40);
    float4 C3 = *(const float4*)(xr + 44);
    float bb[16] = {B0.x,B0.y,B0.z,B0.w,B1.x,B1.y,B1.z,B1.w,
                    B2.x,B2.y,B2.z,B2.w,B3.x,B3.y,B3.z,B3.w};
    float cc[16] = {C0.x,C0.y,C0.z,C0.w,C1.x,C1.y,C1.z,C1.w,
                    C2.x,C2.y,C2.z,C2.w,C3.x,C3.y,C3.z,C3.w};
    float t1 = dt_ * xv;
    float acc = 0.f;
    #pragma unroll
    for (int n = 0; n < 16; ++n) {
      h[n] = fmaf(h[n], __expf(dt_ * An[n]), t1 * bb[n]);
      acc = fmaf(h[n], cc[n], acc);
    }
    float zv = Z[row * 512 + d];
    float sig = 1.f / (1.f + __expf(-zv));
    float val = fmaf(xv, Dd, acc) * (zv * sig);
    u16 hh, ll; bsplit(val, hh, ll);
    yh[row * 512 + d] = hh;
    yl[row * 512 + d] = ll;
  }
}

// ---------------- scatter chunk rows into global emb (fallback) ----------------
template<bool ADD>
__global__ __launch_bounds__(256) void scatter_rows(
    const float* __restrict__ E, float* __restrict__ emb, int l0, int lg) {
  int wv = threadIdx.x >> 6, lane = threadIdx.x & 63;
  int rb = blockIdx.x * 4 + wv;
  size_t grow = ((size_t)(rb >> lg) << 12) + l0 + (rb & ((1 << lg) - 1));
  float4 v = *(const float4*)&E[(size_t)rb * 256 + lane * 4];
  float* dst = &emb[grow * 256 + lane * 4];
  if (ADD) {
    float4 o = *(const float4*)dst;
    v.x += o.x; v.y += o.y; v.z += o.z; v.w += o.w;
  }
  *(float4*)dst = v;
}

// ---------------- final rmsnorm + pooling: wave-per-64-rows, no barriers ----------
__global__ __launch_bounds__(256) void normpool_partial(
    const float* __restrict__ emb, const float* __restrict__ nf,
    float* __restrict__ part) {
  int b = blockIdx.x, cb = blockIdx.y;           // cb 0..15
  int wv = threadIdx.x >> 6, lane = threadIdx.x & 63;
  int p = cb * 4 + wv;                            // 0..63
  float4 acc = make_float4(0.f,0.f,0.f,0.f);
  #pragma unroll 4
  for (int i = 0; i < 64; ++i) {
    size_t row = (size_t)b * 4096 + p * 64 + i;
    float4 v = *(const float4*)&emb[row * 256 + lane * 4];
    float sq = v.x*v.x + v.y*v.y + v.z*v.z + v.w*v.w;
    #pragma unroll
    for (int m = 1; m < 64; m <<= 1) sq += __shfl_xor(sq, m, 64);
    float r = rsqrtf(sq * (1.f / 256.f) + 1e-5f);
    acc.x = fmaf(v.x, r, acc.x);
    acc.y = fmaf(v.y, r, acc.y);
    acc.z = fmaf(v.z, r, acc.z);
    acc.w = fmaf(v.w, r, acc.w);
  }
  float4 w = *(const float4*)&nf[lane * 4];
  acc.x *= w.x; acc.y *= w.y; acc.z *= w.z; acc.w *= w.w;
  *(float4*)&part[((size_t)b * 64 + p) * 256 + lane * 4] = acc;
}

__global__ __launch_bounds__(256) void pool_reduce_kernel(
    const float* __restrict__ part, float* __restrict__ pooled) {
  int b = blockIdx.x, t = threadIdx.x;
  float s = 0.f;
  for (int c = 0; c < 64; ++c) s += part[((size_t)b * 64 + c) * 256 + t];
  pooled[b * 256 + t] = s * (1.f / 4096.f);
}

__global__ __launch_bounds__(128) void head_kernel(
    const float* __restrict__ pooled, const float* __restrict__ hw,
    const float* __restrict__ hb, float* __restrict__ out) {
  int t = threadIdx.x;
  if (t < 80) {
    int b = t / 10, c = t % 10;
    float a = hb[c];
    for (int dd = 0; dd < 256; ++dd) a = fmaf(pooled[b * 256 + dd], hw[c * 256 + dd], a);
    out[t] = a;
  }
}

extern "C" void kernel_launch(void* const* d_in, const int* in_sizes, int n_in,
                              void* d_out, int out_size, void* d_ws, size_t ws_size,
                              hipStream_t stream) {
  const float* x         = (const float*)d_in[0];
  const int*   perm      = (const int*)d_in[1];
  const float* patch_w   = (const float*)d_in[2];
  const float* patch_b   = (const float*)d_in[3];
  const float* norm_w    = (const float*)d_in[4];
  const float* in_proj_w = (const float*)d_in[5];
  const float* conv_w    = (const float*)d_in[6];
  const float* conv_b    = (const float*)d_in[7];
  const float* x_proj_w  = (const float*)d_in[8];
  const float* dt_w      = (const float*)d_in[9];
  const float* dt_b      = (const float*)d_in[10];
  const float* A_log     = (const float*)d_in[11];
  const float* D_skip    = (const float*)d_in[12];
  const float* out_w     = (const float*)d_in[13];
  const float* norm_f    = (const float*)d_in[14];
  const float* head_w    = (const float*)d_in[15];
  const float* head_b    = (const float*)d_in[16];
  float* outp = (float*)d_out;

  const size_t M = (size_t)BATCH * SEQL;  // 32768
  float* ws     = (float*)d_ws;
  float* emb    = ws;                       // M*256
  float* hstate = emb + M * 256;            // 65536
  float* cstate = hstate + 65536;           // 12288
  float* part   = cstate + 12288;           // 8*64*256
  float* pooled = part + 8 * 64 * 256;      // 2048
  float* h_end  = pooled + 2048;            // 64*65536
  float* sdtb   = h_end + 64 * 65536;       // 64*4096
  u16* wi_h = (u16*)(sdtb + 64 * 4096);     // 1024*256
  u16* wi_l = wi_h + 262144;
  u16* wo_h = wi_l + 262144;                // 256*512
  u16* wo_l = wo_h + 131072;
  u16* wx_h = wo_l + 131072;                // 128*512
  u16* wx_l = wx_h + 65536;
  u16* wp_h = wx_l + 65536;                 // 256*192
  u16* wp_l = wp_h + 49152;
  float* cbase = (float*)(wp_l + 49152);

  size_t fixedF = (size_t)(cbase - ws);
  int CL = 4096;
  while (CL > 64) {
    size_t need = (fixedF + (size_t)8 * CL * 2944) * sizeof(float);
    if (need <= ws_size) break;
    CL >>= 1;
  }
  int lg = 31 - __builtin_clz((unsigned)CL);
  int nch = 4096 / CL;
  int CR = 8 * CL;
  int S = CL / 64, TL = 64;
  bool ident = (nch == 1);

  u16*   u_h  = (u16*)cbase;                        // CR*256
  u16*   u_l  = u_h + (size_t)CR * 256;
  float* X    = (float*)(u_l + (size_t)CR * 256);   // CR*512
  float* Z    = X + (size_t)CR * 512;               // CR*512
  u16*   xc_h = (u16*)(Z + (size_t)CR * 512);       // CR*512
  u16*   xc_l = xc_h + (size_t)CR * 512;
  float* xdbl = (float*)(xc_l + (size_t)CR * 512);  // CR*128
  float* dtvb = xdbl + (size_t)CR * 128;            // CR*512
  u16*   y_h  = (u16*)(dtvb + (size_t)CR * 512);    // CR*512
  u16*   y_l  = y_h + (size_t)CR * 512;
  u16*   P_h  = (u16*)X;                            // CR*192 (alias, pre-layer only)
  u16*   P_l  = P_h + (size_t)CR * 192;
  float* E    = Z;                                  // CR*256 (alias)

  // ---- patch embed ----
  convert_split<<<48, 256, 0, stream>>>(patch_w, wp_h, wp_l, 49152);
  for (int c = 0; c < nch; ++c) {
    int l0 = c * CL;
    im2col_chunk<<<CR * 24 / 256, 256, 0, stream>>>(x, perm, P_h, P_l, l0, lg);
    if (ident) {
      gemm128_bf3<true, false, false><<<dim3(2, CR / 128), 256, 0, stream>>>(
          P_h, P_l, wp_h, wp_l, patch_b, emb, nullptr, 256, 192);
    } else {
      gemm128_bf3<true, false, false><<<dim3(2, CR / 128), 256, 0, stream>>>(
          P_h, P_l, wp_h, wp_l, patch_b, E, nullptr, 256, 192);
      scatter_rows<false><<<CR / 4, 256, 0, stream>>>(E, emb, l0, lg);
    }
  }

  // ---- layers ----
  for (int layer = 0; layer < 4; ++layer) {
    convert_split<<<256, 256, 0, stream>>>(in_proj_w + (size_t)layer * 262144, wi_h, wi_l, 262144);
    convert_split<<<128, 256, 0, stream>>>(out_w + (size_t)layer * 131072, wo_h, wo_l, 131072);
    padxp_convert<<<64, 256, 0, stream>>>(x_proj_w + (size_t)layer * 48 * 512, wx_h, wx_l);
    const float* Alog_l = A_log + layer * 8192;
    for (int c = 0; c < nch; ++c) {
      int l0 = c * CL;
      rmsnorm_rows<<<CR / 4, 256, 0, stream>>>(emb, norm_w + layer * 256, u_h, u_l, l0, lg);
      gemm128_bf3<false, false, true><<<dim3(8, CR / 128), 256, 0, stream>>>(
          u_h, u_l, wi_h, wi_l, nullptr, X, Z, 1024, 256);
      conv_chunk<<<CR / 16, 256, 0, stream>>>(
          X, cstate, conv_w + layer * 2048, conv_b + layer * 512, xc_h, xc_l, l0, lg);
      if (!ident) save_hist<<<48, 256, 0, stream>>>(X, cstate, lg);
      gemm128_bf3<false, false, false><<<dim3(1, CR / 128), 256, 0, stream>>>(
          xc_h, xc_l, wx_h, wx_l, nullptr, xdbl, nullptr, 128, 512);
      seg_state<<<dim3(2, 8, S), 256, 0, stream>>>(
          xc_h, xc_l, xdbl, Alog_l, dt_w + layer * 8192, dt_b + layer * 512,
          dtvb, h_end, sdtb, CL, TL);
      seg_combine<<<256, 256, 0, stream>>>(
          h_end, sdtb, Alog_l, hstate, S, c == 0 ? 1 : 0);
      seg_scan<<<dim3(2, 8, S), 256, 0, stream>>>(
          dtvb, xc_h, xc_l, xdbl, Z, Alog_l, D_skip + layer * 512, h_end,
          y_h, y_l, CL, TL);
      if (ident) {
        gemm128_bf3<false, true, false><<<dim3(2, CR / 128), 256, 0, stream>>>(
            y_h, y_l, wo_h, wo_l, nullptr, emb, nullptr, 256, 512);
      } else {
        gemm128_bf3<false, false, false><<<dim3(2, CR / 128), 256, 0, stream>>>(
            y_h, y_l, wo_h, wo_l, nullptr, E, nullptr, 256, 512);
        scatter_rows<true><<<CR / 4, 256, 0, stream>>>(E, emb, l0, lg);
      }
    }
  }

  // ---- final norm + pool + head ----
  normpool_partial<<<dim3(8, 16), 256, 0, stream>>>(emb, norm_f, part);
  pool_reduce_kernel<<<8, 256, 0, stream>>>(part, pooled);
  head_kernel<<<1, 128, 0, stream>>>(pooled, head_w, head_b, outp);
}